// Round 10
// baseline (3304.667 us; speedup 1.0000x reference)
//
#include <hip/hip_runtime.h>
#include <hip/hip_bf16.h>
#include <hip/hip_cooperative_groups.h>

namespace cg = cooperative_groups;

// ---------------------------------------------------------------------------
// GAT with heat-kernel diffusion preprocessing (GDC-style), MI355X.
// CSR build (atomic-free scatter) -> ONE cooperative diffusion kernel
// (10 hops, grid.sync between, fp32 acc in REGISTERS) -> tiled GEMM1 ->
// no-max-softmax agg1 -> ELU -> GEMM2 -> agg2 -> log_softmax.
// Round 10: (a) fuse hops cooperatively, acc never touches memory
// (saves ~1 GB RMW traffic); (b) scatter reuses edge_deg's atomic return
// (epos) -> scatter is atomic-free.
// ---------------------------------------------------------------------------

#define NBLK  1536           // 6 blocks/CU x 256 CU
#define NWAVE (NBLK * 4)     // 6144 waves
#define NMAX  17             // ceil(100000 / 6144); guards handle N<=104448

static __device__ __forceinline__ unsigned pack_bf16x2(float a, float b) {
    __hip_bfloat162 p(__float2bfloat16(a), __float2bfloat16(b));  // a in low 16
    return *reinterpret_cast<unsigned*>(&p);
}

__global__ void init_node_kernel(int* deg, int n) {
    int i = blockIdx.x * 256 + threadIdx.x;
    if (i < n) deg[i] = 1;  // slot 0 reserved for self loop
}

// Counts degree AND records each edge's slot within its dst segment.
__global__ void edge_deg_kernel(const int* __restrict__ dst, int* deg, int* epos, int E) {
    int e = blockIdx.x * 256 + threadIdx.x;
    if (e < E) epos[e] = atomicAdd(&deg[dst[e]], 1);
}

__global__ void alloc_kernel(const int* __restrict__ deg, float* dinv,
                             int* row_off, int* gcount, int n) {
    int i = blockIdx.x * 256 + threadIdx.x;
    if (i >= n) return;
    int dg = deg[i];
    dinv[i] = rsqrtf((float)dg);
    row_off[i] = atomicAdd(gcount, dg);
}

// Atomic-free scatter: slot = row_off[dst] + epos[e]; self loop at slot 0.
__global__ void scatter_kernel(const int* __restrict__ ei, const int* __restrict__ row_off,
                               const int* __restrict__ epos, const float* __restrict__ dinv,
                               int2* __restrict__ csr_pair, int E, int n) {
    int e = blockIdx.x * 256 + threadIdx.x;
    if (e < E) {
        int s = ei[e], d = ei[E + e];
        csr_pair[row_off[d] + epos[e]] = make_int2(s, __float_as_int(dinv[s] * dinv[d]));
    } else if (e < E + n) {
        int i = e - E;
        float di = dinv[i];
        csr_pair[row_off[i]] = make_int2(i, __float_as_int(di * di));
    }
}

// coefs[k][c] = exp(-t_c) * t_c^k / k!
__global__ void coef_kernel(const float* __restrict__ t, float* coefs) {
    int c = threadIdx.x;  // 128 threads
    float tc = t[c];
    float v = expf(-tc);
    coefs[c] = v;
    for (int k = 1; k <= 10; ++k) { v *= tc / (float)k; coefs[k * 128 + c] = v; }
}

// Cooperative fused diffusion: each wave owns nodes {wid + j*NWAVE, j<NMAX}.
// acc (fp32, 2ch/lane) lives in registers for the entire 10-hop sweep.
// NO early returns: every thread reaches every grid.sync().
__global__ __launch_bounds__(256, 6) void diffuse_kernel(
    const int* __restrict__ row_off, const int* __restrict__ deg,
    const int2* __restrict__ csr_pair, const float2* __restrict__ x2,
    const float* __restrict__ coefs, unsigned* __restrict__ hA,
    unsigned* __restrict__ hB, float2* __restrict__ accg, int n) {
    cg::grid_group grid = cg::this_grid();
    int wid = (blockIdx.x << 2) + (threadIdx.x >> 6);
    int lane = threadIdx.x & 63;
    const float2* coefs2 = (const float2*)coefs;

    float2 acc[NMAX];
    // phase 0: acc = c0 * x (regs), h0 = bf16(x)
    float2 c0 = coefs2[lane];
#pragma unroll
    for (int j = 0; j < NMAX; ++j) {
        int node = wid + j * NWAVE;
        if (node < n) {
            float2 xv = x2[(size_t)node * 64 + lane];
            acc[j] = make_float2(c0.x * xv.x, c0.y * xv.y);
            hA[(size_t)node * 64 + lane] = pack_bf16x2(xv.x, xv.y);
        } else {
            acc[j] = make_float2(0.f, 0.f);
        }
    }
    grid.sync();

    const unsigned* cur = hA;
    unsigned* nxt = hB;
#pragma unroll 1
    for (int k = 1; k <= 10; ++k) {
        float2 ck = coefs2[(size_t)k * 64 + lane];
        bool wh = (k < 10);
#pragma unroll
        for (int j = 0; j < NMAX; ++j) {
            int node = wid + j * NWAVE;
            if (node < n) {
                int off = row_off[node];
                int cnt = deg[node];
                float2 a0 = {0.f, 0.f}, a1 = {0.f, 0.f};
                float2 a2 = {0.f, 0.f}, a3 = {0.f, 0.f};
                for (int base = 0; base < cnt; base += 64) {
                    int nb = min(64, cnt - base);
                    int2 p = {0, 0};
                    if (lane < nb) p = csr_pair[off + base + lane];
                    int tt = 0;
                    for (; tt + 3 < nb; tt += 4) {
                        int s0 = __builtin_amdgcn_readlane(p.x, tt);
                        int s1 = __builtin_amdgcn_readlane(p.x, tt + 1);
                        int s2 = __builtin_amdgcn_readlane(p.x, tt + 2);
                        int s3 = __builtin_amdgcn_readlane(p.x, tt + 3);
                        float w0 = __int_as_float(__builtin_amdgcn_readlane(p.y, tt));
                        float w1 = __int_as_float(__builtin_amdgcn_readlane(p.y, tt + 1));
                        float w2 = __int_as_float(__builtin_amdgcn_readlane(p.y, tt + 2));
                        float w3 = __int_as_float(__builtin_amdgcn_readlane(p.y, tt + 3));
                        unsigned u0 = cur[(size_t)s0 * 64 + lane];
                        unsigned u1 = cur[(size_t)s1 * 64 + lane];
                        unsigned u2 = cur[(size_t)s2 * 64 + lane];
                        unsigned u3 = cur[(size_t)s3 * 64 + lane];
                        a0.x = fmaf(w0, __uint_as_float(u0 << 16), a0.x);
                        a0.y = fmaf(w0, __uint_as_float(u0 & 0xffff0000u), a0.y);
                        a1.x = fmaf(w1, __uint_as_float(u1 << 16), a1.x);
                        a1.y = fmaf(w1, __uint_as_float(u1 & 0xffff0000u), a1.y);
                        a2.x = fmaf(w2, __uint_as_float(u2 << 16), a2.x);
                        a2.y = fmaf(w2, __uint_as_float(u2 & 0xffff0000u), a2.y);
                        a3.x = fmaf(w3, __uint_as_float(u3 << 16), a3.x);
                        a3.y = fmaf(w3, __uint_as_float(u3 & 0xffff0000u), a3.y);
                    }
                    for (; tt < nb; ++tt) {
                        int s = __builtin_amdgcn_readlane(p.x, tt);
                        float w = __int_as_float(__builtin_amdgcn_readlane(p.y, tt));
                        unsigned u = cur[(size_t)s * 64 + lane];
                        a0.x = fmaf(w, __uint_as_float(u << 16), a0.x);
                        a0.y = fmaf(w, __uint_as_float(u & 0xffff0000u), a0.y);
                    }
                }
                float2 s;
                s.x = (a0.x + a1.x) + (a2.x + a3.x);
                s.y = (a0.y + a1.y) + (a2.y + a3.y);
                if (wh) nxt[(size_t)node * 64 + lane] = pack_bf16x2(s.x, s.y);
                acc[j].x = fmaf(ck.x, s.x, acc[j].x);
                acc[j].y = fmaf(ck.y, s.y, acc[j].y);
            }
        }
        if (k < 10) grid.sync();
        const unsigned* t = cur; cur = nxt; nxt = (unsigned*)t;
    }
#pragma unroll
    for (int j = 0; j < NMAX; ++j) {
        int node = wid + j * NWAVE;
        if (node < n) accg[(size_t)node * 64 + lane] = acc[j];
    }
}

// h1 = acc @ W1 (128x64) tiled; h1 stored bf16-packed [N,32] uints.
// kc loop unroll(1): full unroll spilled to scratch (round-4 regression).
__global__ __launch_bounds__(256) void gemm1_kernel(
    const float* __restrict__ acc, const float* __restrict__ W1,
    const float* __restrict__ a_s, const float* __restrict__ a_d,
    unsigned* __restrict__ h1b, float* __restrict__ als, float* __restrict__ ald, int n) {
    __shared__ float Wl[128 * 64];
    __shared__ float Al[4][16 * 128];
    for (int i = threadIdx.x; i < 128 * 64; i += 256) Wl[i] = W1[i];
    int w = threadIdx.x >> 6;
    int lane = threadIdx.x & 63;
    int node0 = (blockIdx.x * 4 + w) * 16;
    const float4* accv4 = (const float4*)acc;
    float4* Av4 = (float4*)Al[w];
#pragma unroll
    for (int i = 0; i < 8; ++i) {
        int f4 = i * 64 + lane;
        int g4 = node0 * 32 + f4;
        float4 v = (g4 < n * 32) ? accv4[g4] : make_float4(0.f, 0.f, 0.f, 0.f);
        Av4[f4] = v;
    }
    __syncthreads();
    float sums[16];
#pragma unroll
    for (int nd = 0; nd < 16; ++nd) sums[nd] = 0.f;
#pragma unroll 1
    for (int kc = 0; kc < 16; ++kc) {
        float wr[8];
#pragma unroll
        for (int i = 0; i < 8; ++i) wr[i] = Wl[(kc * 8 + i) * 64 + lane];
#pragma unroll
        for (int nd = 0; nd < 16; ++nd) {
            float4 a = *(const float4*)&Al[w][nd * 128 + kc * 8];
            float4 b = *(const float4*)&Al[w][nd * 128 + kc * 8 + 4];
            float s = sums[nd];
            s = fmaf(wr[0], a.x, s); s = fmaf(wr[1], a.y, s);
            s = fmaf(wr[2], a.z, s); s = fmaf(wr[3], a.w, s);
            s = fmaf(wr[4], b.x, s); s = fmaf(wr[5], b.y, s);
            s = fmaf(wr[6], b.z, s); s = fmaf(wr[7], b.w, s);
            sums[nd] = s;
        }
    }
    float asv = a_s[lane], adv = a_d[lane];
#pragma unroll
    for (int nd = 0; nd < 16; ++nd) {
        int node = node0 + nd;
        if (node >= n) break;
        float sum = sums[nd];
        float partner = __shfl_xor(sum, 1);
        if ((lane & 1) == 0) h1b[(size_t)node * 32 + (lane >> 1)] = pack_bf16x2(sum, partner);
        float vs = sum * asv;
        float vd = sum * adv;
        vs += __shfl_xor(vs, 1); vs += __shfl_xor(vs, 2); vs += __shfl_xor(vs, 4);
        vd += __shfl_xor(vd, 1); vd += __shfl_xor(vd, 2); vd += __shfl_xor(vd, 4);
        if ((lane & 7) == 0) {
            als[(size_t)node * 8 + (lane >> 3)] = vs;
            ald[(size_t)node * 8 + (lane >> 3)] = vd;
        }
    }
}

// agg1: softmax agg without max subtraction (shift-invariant; logits O(1)).
// Half-wave edge parallelism; channel pair (2l,2l+1) bf16-packed per lane.
__global__ void agg1_kernel(const int* __restrict__ row_off, const int* __restrict__ deg,
                            const int2* __restrict__ csr_pair,
                            const unsigned* __restrict__ h1b, const float* __restrict__ als,
                            const float* __restrict__ ald, const float* __restrict__ b1,
                            float2* __restrict__ helu2, int n) {
    int wid = (blockIdx.x << 2) + (threadIdx.x >> 6);
    int lane = threadIdx.x & 63;
    if (wid >= n) return;
    int half = lane >> 5;
    int l = lane & 31;          // channel pair index
    int head = l >> 2;          // (2l)>>3
    int off = row_off[wid];
    int cnt = deg[wid];
    float aldv = ald[(size_t)wid * 8 + head];
    float dA = 0.f, dB = 0.f;
    float2 aA = {0.f, 0.f}, aB = {0.f, 0.f};
    for (int base = 0; base < cnt; base += 64) {
        int nb = min(64, cnt - base);
        int srcv = 0;
        if (lane < nb) srcv = csr_pair[off + base + lane].x;
        int j = 0;
        for (; j + 3 < nb; j += 4) {
            int sA0 = __builtin_amdgcn_readlane(srcv, j);
            int sA1 = __builtin_amdgcn_readlane(srcv, j + 1);
            int sB0 = __builtin_amdgcn_readlane(srcv, j + 2);
            int sB1 = __builtin_amdgcn_readlane(srcv, j + 3);
            int sA = half ? sA1 : sA0;
            int sB = half ? sB1 : sB0;
            float eA = als[(size_t)sA * 8 + head] + aldv;
            float eB = als[(size_t)sB * 8 + head] + aldv;
            eA = eA > 0.f ? eA : 0.2f * eA;
            eB = eB > 0.f ? eB : 0.2f * eB;
            float pA = __expf(eA);
            float pB = __expf(eB);
            unsigned uA = h1b[(size_t)sA * 32 + l];
            unsigned uB = h1b[(size_t)sB * 32 + l];
            dA += pA; dB += pB;
            aA.x = fmaf(pA, __uint_as_float(uA << 16), aA.x);
            aA.y = fmaf(pA, __uint_as_float(uA & 0xffff0000u), aA.y);
            aB.x = fmaf(pB, __uint_as_float(uB << 16), aB.x);
            aB.y = fmaf(pB, __uint_as_float(uB & 0xffff0000u), aB.y);
        }
        for (; j < nb; j += 2) {
            int s0 = __builtin_amdgcn_readlane(srcv, j);
            int s1 = (j + 1 < nb) ? __builtin_amdgcn_readlane(srcv, j + 1) : -1;
            int s = half ? s1 : s0;
            bool valid = s >= 0;
            int ss = valid ? s : 0;
            float e = als[(size_t)ss * 8 + head] + aldv;
            e = e > 0.f ? e : 0.2f * e;
            float p = valid ? __expf(e) : 0.f;
            unsigned u = h1b[(size_t)ss * 32 + l];
            dA += p;
            aA.x = fmaf(p, __uint_as_float(u << 16), aA.x);
            aA.y = fmaf(p, __uint_as_float(u & 0xffff0000u), aA.y);
        }
    }
    float d = dA + dB;
    float2 accv = make_float2(aA.x + aB.x, aA.y + aB.y);
    d += __shfl_xor(d, 32);
    accv.x += __shfl_xor(accv.x, 32);
    accv.y += __shfl_xor(accv.y, 32);
    if (half == 0) {
        float inv = 1.f / d;   // d >= exp(self-loop logit) > 0
        float ox = fmaf(accv.x, inv, b1[2 * l]);
        float oy = fmaf(accv.y, inv, b1[2 * l + 1]);
        ox = ox > 0.f ? ox : expm1f(ox);  // ELU
        oy = oy > 0.f ? oy : expm1f(oy);
        helu2[(size_t)wid * 32 + l] = make_float2(ox, oy);
    }
}

// h2 = helu @ W2 (64x40) tiled; h2 stored bf16-packed [N,20] uints.
__global__ __launch_bounds__(256) void gemm2_kernel(
    const float* __restrict__ helu, const float* __restrict__ W2,
    const float* __restrict__ a_s, const float* __restrict__ a_d,
    unsigned* __restrict__ h2b, float* __restrict__ als, float* __restrict__ ald, int n) {
    __shared__ float Wl[64 * 40];
    __shared__ float Al[4][16 * 64];
    for (int i = threadIdx.x; i < 64 * 40; i += 256) Wl[i] = W2[i];
    int w = threadIdx.x >> 6;
    int lane = threadIdx.x & 63;
    int node0 = (blockIdx.x * 4 + w) * 16;
    const float4* hv4 = (const float4*)helu;
    float4* Av4 = (float4*)Al[w];
#pragma unroll
    for (int i = 0; i < 4; ++i) {
        int f4 = i * 64 + lane;
        int g4 = node0 * 16 + f4;
        float4 v = (g4 < n * 16) ? hv4[g4] : make_float4(0.f, 0.f, 0.f, 0.f);
        Av4[f4] = v;
    }
    __syncthreads();
    bool act = lane < 40;
    int li = act ? lane : 0;
    float sums[16];
#pragma unroll
    for (int nd = 0; nd < 16; ++nd) sums[nd] = 0.f;
#pragma unroll 1
    for (int kc = 0; kc < 8; ++kc) {
        float wr[8];
#pragma unroll
        for (int i = 0; i < 8; ++i) wr[i] = Wl[(kc * 8 + i) * 40 + li];
#pragma unroll
        for (int nd = 0; nd < 16; ++nd) {
            float4 a = *(const float4*)&Al[w][nd * 64 + kc * 8];
            float4 b = *(const float4*)&Al[w][nd * 64 + kc * 8 + 4];
            float s = sums[nd];
            s = fmaf(wr[0], a.x, s); s = fmaf(wr[1], a.y, s);
            s = fmaf(wr[2], a.z, s); s = fmaf(wr[3], a.w, s);
            s = fmaf(wr[4], b.x, s); s = fmaf(wr[5], b.y, s);
            s = fmaf(wr[6], b.z, s); s = fmaf(wr[7], b.w, s);
            sums[nd] = s;
        }
    }
    float asv = act ? a_s[lane] : 0.f;
    float adv = act ? a_d[lane] : 0.f;
#pragma unroll
    for (int nd = 0; nd < 16; ++nd) {
        int node = node0 + nd;
        if (node >= n) break;
        float sum = sums[nd];
        float partner = __shfl_xor(sum, 1);
        if (act && (lane & 1) == 0) h2b[(size_t)node * 20 + (lane >> 1)] = pack_bf16x2(sum, partner);
        float vs = act ? sum * asv : 0.f;
        float vd = act ? sum * adv : 0.f;
#pragma unroll
        for (int i = 32; i >= 1; i >>= 1) { vs += __shfl_xor(vs, i); vd += __shfl_xor(vd, i); }
        if (lane == 0) { als[node] = vs; ald[node] = vd; }
    }
}

// agg2 (1 head, 40 ch) no-max softmax + half-wave edge split + log_softmax.
__global__ void agg2_kernel(const int* __restrict__ row_off, const int* __restrict__ deg,
                            const int2* __restrict__ csr_pair,
                            const unsigned* __restrict__ h2b, const float* __restrict__ als,
                            const float* __restrict__ ald, const float* __restrict__ b2,
                            float* __restrict__ out, int n) {
    int wid = (blockIdx.x << 2) + (threadIdx.x >> 6);
    int lane = threadIdx.x & 63;
    if (wid >= n) return;
    int half = lane >> 5;
    int l = lane & 31;
    bool act = l < 20;          // channel pairs 0..19
    int li = act ? l : 0;
    int off = row_off[wid];
    int cnt = deg[wid];
    float aldv = ald[wid];
    float dA = 0.f, dB = 0.f;
    float2 aA = {0.f, 0.f}, aB = {0.f, 0.f};
    for (int base = 0; base < cnt; base += 64) {
        int nb = min(64, cnt - base);
        int srcv = 0;
        if (lane < nb) srcv = csr_pair[off + base + lane].x;
        int j = 0;
        for (; j + 3 < nb; j += 4) {
            int sA0 = __builtin_amdgcn_readlane(srcv, j);
            int sA1 = __builtin_amdgcn_readlane(srcv, j + 1);
            int sB0 = __builtin_amdgcn_readlane(srcv, j + 2);
            int sB1 = __builtin_amdgcn_readlane(srcv, j + 3);
            int sA = half ? sA1 : sA0;
            int sB = half ? sB1 : sB0;
            float eA = als[sA] + aldv;
            float eB = als[sB] + aldv;
            eA = eA > 0.f ? eA : 0.2f * eA;
            eB = eB > 0.f ? eB : 0.2f * eB;
            float pA = __expf(eA);
            float pB = __expf(eB);
            unsigned uA = h2b[(size_t)sA * 20 + li];
            unsigned uB = h2b[(size_t)sB * 20 + li];
            dA += pA; dB += pB;
            aA.x = fmaf(pA, __uint_as_float(uA << 16), aA.x);
            aA.y = fmaf(pA, __uint_as_float(uA & 0xffff0000u), aA.y);
            aB.x = fmaf(pB, __uint_as_float(uB << 16), aB.x);
            aB.y = fmaf(pB, __uint_as_float(uB & 0xffff0000u), aB.y);
        }
        for (; j < nb; j += 2) {
            int s0 = __builtin_amdgcn_readlane(srcv, j);
            int s1 = (j + 1 < nb) ? __builtin_amdgcn_readlane(srcv, j + 1) : -1;
            int s = half ? s1 : s0;
            bool valid = s >= 0;
            int ss = valid ? s : 0;
            float e = als[ss] + aldv;
            e = e > 0.f ? e : 0.2f * e;
            float p = valid ? __expf(e) : 0.f;
            unsigned u = h2b[(size_t)ss * 20 + li];
            dA += p;
            aA.x = fmaf(p, __uint_as_float(u << 16), aA.x);
            aA.y = fmaf(p, __uint_as_float(u & 0xffff0000u), aA.y);
        }
    }
    float d = dA + dB;
    float2 accv = make_float2(aA.x + aB.x, aA.y + aB.y);
    d += __shfl_xor(d, 32);
    accv.x += __shfl_xor(accv.x, 32);
    accv.y += __shfl_xor(accv.y, 32);
    float inv = 1.f / d;
    bool live = (half == 0) && act;
    float ox = live ? fmaf(accv.x, inv, b2[2 * l]) : -1e30f;
    float oy = live ? fmaf(accv.y, inv, b2[2 * l + 1]) : -1e30f;
    float vv = fmaxf(ox, oy);
#pragma unroll
    for (int i = 16; i >= 1; i >>= 1) vv = fmaxf(vv, __shfl_xor(vv, i));
    float ex = live ? (__expf(ox - vv) + __expf(oy - vv)) : 0.f;
#pragma unroll
    for (int i = 16; i >= 1; i >>= 1) ex += __shfl_xor(ex, i);
    if (live) {
        float lse = vv + logf(ex);
        *(float2*)&out[(size_t)wid * 40 + 2 * l] = make_float2(ox - lse, oy - lse);
    }
}

extern "C" void kernel_launch(void* const* d_in, const int* in_sizes, int n_in,
                              void* d_out, int out_size, void* d_ws, size_t ws_size,
                              hipStream_t stream) {
    const float* x    = (const float*)d_in[0];
    const int*   ei   = (const int*)d_in[1];
    const float* t    = (const float*)d_in[2];
    const float* W1   = (const float*)d_in[3];
    const float* a_s1 = (const float*)d_in[4];
    const float* a_d1 = (const float*)d_in[5];
    const float* b1   = (const float*)d_in[6];
    const float* W2   = (const float*)d_in[7];
    const float* a_s2 = (const float*)d_in[8];
    const float* a_d2 = (const float*)d_in[9];
    const float* b2   = (const float*)d_in[10];
    float* out = (float*)d_out;

    const int N = in_sizes[0] / 128;
    const int E = in_sizes[1] / 2;

    char* w = (char*)d_ws;
    auto carve = [&](size_t bytes) {
        void* p = (void*)w;
        w += (bytes + 255) & ~(size_t)255;
        return p;
    };
    int*      deg      = (int*)carve((size_t)N * 4);
    int*      row_off  = (int*)carve((size_t)N * 4);
    int*      gcount   = (int*)carve(256);
    float*    dinv     = (float*)carve((size_t)N * 4);
    int*      epos     = (int*)carve((size_t)E * 4);
    int2*     csr_pair = (int2*)carve((size_t)(E + N) * 8);
    float*    coefs    = (float*)carve(11 * 128 * 4);
    float*    als1     = (float*)carve((size_t)N * 8 * 4);
    float*    ald1     = (float*)carve((size_t)N * 8 * 4);
    float*    als2     = (float*)carve((size_t)N * 4);
    float*    ald2     = (float*)carve((size_t)N * 4);
    unsigned* hA       = (unsigned*)carve((size_t)N * 64 * 4);  // bf16x2 per uint
    unsigned* hB       = (unsigned*)carve((size_t)N * 64 * 4);
    float*    acc      = (float*)carve((size_t)N * 128 * 4);
    unsigned* h1b      = (unsigned*)carve((size_t)N * 32 * 4);  // bf16 [N,64]
    float*    helu     = (float*)carve((size_t)N * 64 * 4);
    unsigned* h2b      = (unsigned*)carve((size_t)N * 20 * 4);  // bf16 [N,40]

    dim3 blk(256);
    int gN = (N + 255) / 256;
    int gE = (E + 255) / 256;
    int gEN = (E + N + 255) / 256;
    int gW = (N + 3) / 4;        // one wave per node, 4 waves/block
    int gT = (N + 63) / 64;      // wave per 16 nodes, 4 waves/block

    init_node_kernel<<<gN, blk, 0, stream>>>(deg, N);
    hipMemsetAsync(gcount, 0, 4, stream);
    edge_deg_kernel<<<gE, blk, 0, stream>>>(ei + E, deg, epos, E);
    alloc_kernel<<<gN, blk, 0, stream>>>(deg, dinv, row_off, gcount, N);
    scatter_kernel<<<gEN, blk, 0, stream>>>(ei, row_off, epos, dinv, csr_pair, E, N);
    coef_kernel<<<1, 128, 0, stream>>>(t, coefs);

    // cooperative fused diffusion (10 hops, acc in registers)
    {
        const float2* x2v = (const float2*)x;
        float2* acc2v = (float2*)acc;
        int Nv = N;
        const int* row_off_v = row_off;
        const int* deg_v = deg;
        const int2* csr_v = csr_pair;
        const float* coefs_v = coefs;
        unsigned* hA_v = hA;
        unsigned* hB_v = hB;
        void* kargs[] = {(void*)&row_off_v, (void*)&deg_v, (void*)&csr_v, (void*)&x2v,
                         (void*)&coefs_v, (void*)&hA_v, (void*)&hB_v, (void*)&acc2v,
                         (void*)&Nv};
        hipLaunchCooperativeKernel((const void*)diffuse_kernel, dim3(NBLK), dim3(256),
                                   kargs, 0, stream);
    }

    gemm1_kernel<<<gT, blk, 0, stream>>>(acc, W1, a_s1, a_d1, h1b, als1, ald1, N);
    agg1_kernel<<<gW, blk, 0, stream>>>(row_off, deg, csr_pair, h1b, als1, ald1, b1,
                                        (float2*)helu, N);
    gemm2_kernel<<<gT, blk, 0, stream>>>(helu, W2, a_s2, a_d2, h2b, als2, ald2, N);
    agg2_kernel<<<gW, blk, 0, stream>>>(row_off, deg, csr_pair, h2b, als2, ald2, b2, out, N);
}

// Round 12
// 1274.302 us; speedup vs baseline: 2.5933x; 2.5933x over previous
//
#include <hip/hip_runtime.h>
#include <hip/hip_bf16.h>

// ---------------------------------------------------------------------------
// GAT with heat-kernel diffusion preprocessing (GDC-style), MI355X.
// CSR build (atomic-free scatter via epos) -> 10x separate diffusion hops
// (bf16 h_k buffers, NO acc RMW) -> streaming combine acc = sum coef_k h_k ->
// tiled GEMM1 -> no-max-softmax agg1 -> ELU -> GEMM2 -> agg2 -> log_softmax.
// Round 11: revert cooperative fusion (static wave assignment + grid barriers
// lost dynamic load balancing: 3.9 -> 1.14 TB/s). Separate hops + h_k
// storage removes the 1.02 GB fp32 acc read-modify-write instead.
// ---------------------------------------------------------------------------

static __device__ __forceinline__ unsigned pack_bf16x2(float a, float b) {
    __hip_bfloat162 p(__float2bfloat16(a), __float2bfloat16(b));  // a in low 16
    return *reinterpret_cast<unsigned*>(&p);
}

__global__ void init_node_kernel(int* deg, int n) {
    int i = blockIdx.x * 256 + threadIdx.x;
    if (i < n) deg[i] = 1;  // slot 0 reserved for self loop
}

// Counts degree AND records each edge's slot within its dst segment.
__global__ void edge_deg_kernel(const int* __restrict__ dst, int* deg, int* epos, int E) {
    int e = blockIdx.x * 256 + threadIdx.x;
    if (e < E) epos[e] = atomicAdd(&deg[dst[e]], 1);
}

__global__ void alloc_kernel(const int* __restrict__ deg, float* dinv,
                             int* row_off, int* gcount, int n) {
    int i = blockIdx.x * 256 + threadIdx.x;
    if (i >= n) return;
    int dg = deg[i];
    dinv[i] = rsqrtf((float)dg);
    row_off[i] = atomicAdd(gcount, dg);
}

// Atomic-free scatter: slot = row_off[dst] + epos[e]; self loop at slot 0.
__global__ void scatter_kernel(const int* __restrict__ ei, const int* __restrict__ row_off,
                               const int* __restrict__ epos, const float* __restrict__ dinv,
                               int2* __restrict__ csr_pair, int E, int n) {
    int e = blockIdx.x * 256 + threadIdx.x;
    if (e < E) {
        int s = ei[e], d = ei[E + e];
        csr_pair[row_off[d] + epos[e]] = make_int2(s, __float_as_int(dinv[s] * dinv[d]));
    } else if (e < E + n) {
        int i = e - E;
        float di = dinv[i];
        csr_pair[row_off[i]] = make_int2(i, __float_as_int(di * di));
    }
}

// coefs[k][c] = exp(-t_c) * t_c^k / k!
__global__ void coef_kernel(const float* __restrict__ t, float* coefs) {
    int c = threadIdx.x;  // 128 threads
    float tc = t[c];
    float v = expf(-tc);
    coefs[c] = v;
    for (int k = 1; k <= 10; ++k) { v *= tc / (float)k; coefs[k * 128 + c] = v; }
}

// Path A init: h0 = bf16(x) only (combine builds acc later).
__global__ void init_diff_a_kernel(const float4* __restrict__ x4, uint2* __restrict__ h0,
                                   int total4) {
    int i = blockIdx.x * 256 + threadIdx.x;
    if (i >= total4) return;
    float4 xv = x4[i];
    h0[i] = make_uint2(pack_bf16x2(xv.x, xv.y), pack_bf16x2(xv.z, xv.w));
}

// Path B init: h0 = bf16(x), acc = c0*x (round-9 behavior).
__global__ void init_diff_b_kernel(const float4* __restrict__ x4, const float* __restrict__ coefs,
                                   uint2* __restrict__ h0, float4* __restrict__ acc4, int total4) {
    int i = blockIdx.x * 256 + threadIdx.x;
    if (i >= total4) return;
    float4 xv = x4[i];
    h0[i] = make_uint2(pack_bf16x2(xv.x, xv.y), pack_bf16x2(xv.z, xv.w));
    const float4 c = *(const float4*)&coefs[(i & 31) * 4];
    acc4[i] = make_float4(c.x * xv.x, c.y * xv.y, c.z * xv.z, c.w * xv.w);
}

// Shared gather: s = (A_hat h)[node], 2 channels/lane, 8 loads in flight.
static __device__ __forceinline__ float2 gather_row(
    const int* __restrict__ row_off, const int* __restrict__ deg,
    const int2* __restrict__ csr_pair, const unsigned* __restrict__ h,
    int wid, int lane) {
    int off = row_off[wid];
    int cnt = deg[wid];
    float2 a0 = {0.f, 0.f}, a1 = {0.f, 0.f}, a2 = {0.f, 0.f}, a3 = {0.f, 0.f};
    for (int base = 0; base < cnt; base += 64) {
        int nb = min(64, cnt - base);
        int2 p = {0, 0};
        if (lane < nb) p = csr_pair[off + base + lane];
        int tt = 0;
        for (; tt + 7 < nb; tt += 8) {
            int s0 = __builtin_amdgcn_readlane(p.x, tt);
            int s1 = __builtin_amdgcn_readlane(p.x, tt + 1);
            int s2 = __builtin_amdgcn_readlane(p.x, tt + 2);
            int s3 = __builtin_amdgcn_readlane(p.x, tt + 3);
            int s4 = __builtin_amdgcn_readlane(p.x, tt + 4);
            int s5 = __builtin_amdgcn_readlane(p.x, tt + 5);
            int s6 = __builtin_amdgcn_readlane(p.x, tt + 6);
            int s7 = __builtin_amdgcn_readlane(p.x, tt + 7);
            float w0 = __int_as_float(__builtin_amdgcn_readlane(p.y, tt));
            float w1 = __int_as_float(__builtin_amdgcn_readlane(p.y, tt + 1));
            float w2 = __int_as_float(__builtin_amdgcn_readlane(p.y, tt + 2));
            float w3 = __int_as_float(__builtin_amdgcn_readlane(p.y, tt + 3));
            float w4 = __int_as_float(__builtin_amdgcn_readlane(p.y, tt + 4));
            float w5 = __int_as_float(__builtin_amdgcn_readlane(p.y, tt + 5));
            float w6 = __int_as_float(__builtin_amdgcn_readlane(p.y, tt + 6));
            float w7 = __int_as_float(__builtin_amdgcn_readlane(p.y, tt + 7));
            unsigned u0 = h[(size_t)s0 * 64 + lane];
            unsigned u1 = h[(size_t)s1 * 64 + lane];
            unsigned u2 = h[(size_t)s2 * 64 + lane];
            unsigned u3 = h[(size_t)s3 * 64 + lane];
            unsigned u4 = h[(size_t)s4 * 64 + lane];
            unsigned u5 = h[(size_t)s5 * 64 + lane];
            unsigned u6 = h[(size_t)s6 * 64 + lane];
            unsigned u7 = h[(size_t)s7 * 64 + lane];
            a0.x = fmaf(w0, __uint_as_float(u0 << 16), a0.x);
            a0.y = fmaf(w0, __uint_as_float(u0 & 0xffff0000u), a0.y);
            a1.x = fmaf(w1, __uint_as_float(u1 << 16), a1.x);
            a1.y = fmaf(w1, __uint_as_float(u1 & 0xffff0000u), a1.y);
            a2.x = fmaf(w2, __uint_as_float(u2 << 16), a2.x);
            a2.y = fmaf(w2, __uint_as_float(u2 & 0xffff0000u), a2.y);
            a3.x = fmaf(w3, __uint_as_float(u3 << 16), a3.x);
            a3.y = fmaf(w3, __uint_as_float(u3 & 0xffff0000u), a3.y);
            a0.x = fmaf(w4, __uint_as_float(u4 << 16), a0.x);
            a0.y = fmaf(w4, __uint_as_float(u4 & 0xffff0000u), a0.y);
            a1.x = fmaf(w5, __uint_as_float(u5 << 16), a1.x);
            a1.y = fmaf(w5, __uint_as_float(u5 & 0xffff0000u), a1.y);
            a2.x = fmaf(w6, __uint_as_float(u6 << 16), a2.x);
            a2.y = fmaf(w6, __uint_as_float(u6 & 0xffff0000u), a2.y);
            a3.x = fmaf(w7, __uint_as_float(u7 << 16), a3.x);
            a3.y = fmaf(w7, __uint_as_float(u7 & 0xffff0000u), a3.y);
        }
        for (; tt < nb; ++tt) {
            int s = __builtin_amdgcn_readlane(p.x, tt);
            float w = __int_as_float(__builtin_amdgcn_readlane(p.y, tt));
            unsigned u = h[(size_t)s * 64 + lane];
            a0.x = fmaf(w, __uint_as_float(u << 16), a0.x);
            a0.y = fmaf(w, __uint_as_float(u & 0xffff0000u), a0.y);
        }
    }
    float2 s;
    s.x = (a0.x + a1.x) + (a2.x + a3.x);
    s.y = (a0.y + a1.y) + (a2.y + a3.y);
    return s;
}

// Path A hop: h_out = bf16(A_hat h_prev). No acc traffic.
__global__ void hop_a_kernel(const int* __restrict__ row_off, const int* __restrict__ deg,
                             const int2* __restrict__ csr_pair,
                             const unsigned* __restrict__ h_prev, unsigned* __restrict__ h_out,
                             int n) {
    int wid = (blockIdx.x << 2) + (threadIdx.x >> 6);
    int lane = threadIdx.x & 63;
    if (wid >= n) return;
    float2 s = gather_row(row_off, deg, csr_pair, h_prev, wid, lane);
    h_out[(size_t)wid * 64 + lane] = pack_bf16x2(s.x, s.y);
}

// Path B hop: round-9 behavior (acc RMW fused).
__global__ void hop_b_kernel(const int* __restrict__ row_off, const int* __restrict__ deg,
                             const int2* __restrict__ csr_pair,
                             const unsigned* __restrict__ h_prev, unsigned* __restrict__ h_out,
                             float2* __restrict__ acc2, const float2* __restrict__ coefk2,
                             int n, int write_h) {
    int wid = (blockIdx.x << 2) + (threadIdx.x >> 6);
    int lane = threadIdx.x & 63;
    if (wid >= n) return;
    float2 s = gather_row(row_off, deg, csr_pair, h_prev, wid, lane);
    size_t o = (size_t)wid * 64 + lane;
    if (write_h) h_out[o] = pack_bf16x2(s.x, s.y);
    float2 c = coefk2[lane];
    float2 av = acc2[o];
    av.x = fmaf(c.x, s.x, av.x);
    av.y = fmaf(c.y, s.y, av.y);
    acc2[o] = av;
}

// Path A combine: acc = c0*x + sum_{k=1..10} ck * h_k. Pure streaming.
__global__ void combine_kernel(const float2* __restrict__ x2, const float* __restrict__ coefs,
                               const unsigned* __restrict__ hseq, size_t stride,
                               float2* __restrict__ acc2, int total) {
    int i = blockIdx.x * 256 + threadIdx.x;
    if (i >= total) return;
    int c2 = i & 63;
    const float2* coefs2 = (const float2*)coefs;
    float2 c0 = coefs2[c2];
    float2 xv = x2[i];
    float2 a = make_float2(c0.x * xv.x, c0.y * xv.y);
#pragma unroll
    for (int k = 1; k <= 10; ++k) {
        float2 ck = coefs2[(size_t)k * 64 + c2];
        unsigned u = hseq[(size_t)k * stride + i];
        a.x = fmaf(ck.x, __uint_as_float(u << 16), a.x);
        a.y = fmaf(ck.y, __uint_as_float(u & 0xffff0000u), a.y);
    }
    acc2[i] = a;
}

// h1 = acc @ W1 (128x64) tiled; h1 stored bf16-packed [N,32] uints.
// kc loop unroll(1): full unroll spilled to scratch (round-4 regression).
__global__ __launch_bounds__(256) void gemm1_kernel(
    const float* __restrict__ acc, const float* __restrict__ W1,
    const float* __restrict__ a_s, const float* __restrict__ a_d,
    unsigned* __restrict__ h1b, float* __restrict__ als, float* __restrict__ ald, int n) {
    __shared__ float Wl[128 * 64];
    __shared__ float Al[4][16 * 128];
    for (int i = threadIdx.x; i < 128 * 64; i += 256) Wl[i] = W1[i];
    int w = threadIdx.x >> 6;
    int lane = threadIdx.x & 63;
    int node0 = (blockIdx.x * 4 + w) * 16;
    const float4* accv4 = (const float4*)acc;
    float4* Av4 = (float4*)Al[w];
#pragma unroll
    for (int i = 0; i < 8; ++i) {
        int f4 = i * 64 + lane;
        int g4 = node0 * 32 + f4;
        float4 v = (g4 < n * 32) ? accv4[g4] : make_float4(0.f, 0.f, 0.f, 0.f);
        Av4[f4] = v;
    }
    __syncthreads();
    float sums[16];
#pragma unroll
    for (int nd = 0; nd < 16; ++nd) sums[nd] = 0.f;
#pragma unroll 1
    for (int kc = 0; kc < 16; ++kc) {
        float wr[8];
#pragma unroll
        for (int i = 0; i < 8; ++i) wr[i] = Wl[(kc * 8 + i) * 64 + lane];
#pragma unroll
        for (int nd = 0; nd < 16; ++nd) {
            float4 a = *(const float4*)&Al[w][nd * 128 + kc * 8];
            float4 b = *(const float4*)&Al[w][nd * 128 + kc * 8 + 4];
            float s = sums[nd];
            s = fmaf(wr[0], a.x, s); s = fmaf(wr[1], a.y, s);
            s = fmaf(wr[2], a.z, s); s = fmaf(wr[3], a.w, s);
            s = fmaf(wr[4], b.x, s); s = fmaf(wr[5], b.y, s);
            s = fmaf(wr[6], b.z, s); s = fmaf(wr[7], b.w, s);
            sums[nd] = s;
        }
    }
    float asv = a_s[lane], adv = a_d[lane];
#pragma unroll
    for (int nd = 0; nd < 16; ++nd) {
        int node = node0 + nd;
        if (node >= n) break;
        float sum = sums[nd];
        float partner = __shfl_xor(sum, 1);
        if ((lane & 1) == 0) h1b[(size_t)node * 32 + (lane >> 1)] = pack_bf16x2(sum, partner);
        float vs = sum * asv;
        float vd = sum * adv;
        vs += __shfl_xor(vs, 1); vs += __shfl_xor(vs, 2); vs += __shfl_xor(vs, 4);
        vd += __shfl_xor(vd, 1); vd += __shfl_xor(vd, 2); vd += __shfl_xor(vd, 4);
        if ((lane & 7) == 0) {
            als[(size_t)node * 8 + (lane >> 3)] = vs;
            ald[(size_t)node * 8 + (lane >> 3)] = vd;
        }
    }
}

// agg1: softmax agg without max subtraction (shift-invariant; logits O(1)).
// Half-wave edge parallelism; channel pair (2l,2l+1) bf16-packed per lane.
__global__ void agg1_kernel(const int* __restrict__ row_off, const int* __restrict__ deg,
                            const int2* __restrict__ csr_pair,
                            const unsigned* __restrict__ h1b, const float* __restrict__ als,
                            const float* __restrict__ ald, const float* __restrict__ b1,
                            float2* __restrict__ helu2, int n) {
    int wid = (blockIdx.x << 2) + (threadIdx.x >> 6);
    int lane = threadIdx.x & 63;
    if (wid >= n) return;
    int half = lane >> 5;
    int l = lane & 31;          // channel pair index
    int head = l >> 2;          // (2l)>>3
    int off = row_off[wid];
    int cnt = deg[wid];
    float aldv = ald[(size_t)wid * 8 + head];
    float dA = 0.f, dB = 0.f;
    float2 aA = {0.f, 0.f}, aB = {0.f, 0.f};
    for (int base = 0; base < cnt; base += 64) {
        int nb = min(64, cnt - base);
        int srcv = 0;
        if (lane < nb) srcv = csr_pair[off + base + lane].x;
        int j = 0;
        for (; j + 3 < nb; j += 4) {
            int sA0 = __builtin_amdgcn_readlane(srcv, j);
            int sA1 = __builtin_amdgcn_readlane(srcv, j + 1);
            int sB0 = __builtin_amdgcn_readlane(srcv, j + 2);
            int sB1 = __builtin_amdgcn_readlane(srcv, j + 3);
            int sA = half ? sA1 : sA0;
            int sB = half ? sB1 : sB0;
            float eA = als[(size_t)sA * 8 + head] + aldv;
            float eB = als[(size_t)sB * 8 + head] + aldv;
            eA = eA > 0.f ? eA : 0.2f * eA;
            eB = eB > 0.f ? eB : 0.2f * eB;
            float pA = __expf(eA);
            float pB = __expf(eB);
            unsigned uA = h1b[(size_t)sA * 32 + l];
            unsigned uB = h1b[(size_t)sB * 32 + l];
            dA += pA; dB += pB;
            aA.x = fmaf(pA, __uint_as_float(uA << 16), aA.x);
            aA.y = fmaf(pA, __uint_as_float(uA & 0xffff0000u), aA.y);
            aB.x = fmaf(pB, __uint_as_float(uB << 16), aB.x);
            aB.y = fmaf(pB, __uint_as_float(uB & 0xffff0000u), aB.y);
        }
        for (; j < nb; j += 2) {
            int s0 = __builtin_amdgcn_readlane(srcv, j);
            int s1 = (j + 1 < nb) ? __builtin_amdgcn_readlane(srcv, j + 1) : -1;
            int s = half ? s1 : s0;
            bool valid = s >= 0;
            int ss = valid ? s : 0;
            float e = als[(size_t)ss * 8 + head] + aldv;
            e = e > 0.f ? e : 0.2f * e;
            float p = valid ? __expf(e) : 0.f;
            unsigned u = h1b[(size_t)ss * 32 + l];
            dA += p;
            aA.x = fmaf(p, __uint_as_float(u << 16), aA.x);
            aA.y = fmaf(p, __uint_as_float(u & 0xffff0000u), aA.y);
        }
    }
    float d = dA + dB;
    float2 accv = make_float2(aA.x + aB.x, aA.y + aB.y);
    d += __shfl_xor(d, 32);
    accv.x += __shfl_xor(accv.x, 32);
    accv.y += __shfl_xor(accv.y, 32);
    if (half == 0) {
        float inv = 1.f / d;   // d >= exp(self-loop logit) > 0
        float ox = fmaf(accv.x, inv, b1[2 * l]);
        float oy = fmaf(accv.y, inv, b1[2 * l + 1]);
        ox = ox > 0.f ? ox : expm1f(ox);  // ELU
        oy = oy > 0.f ? oy : expm1f(oy);
        helu2[(size_t)wid * 32 + l] = make_float2(ox, oy);
    }
}

// h2 = helu @ W2 (64x40) tiled; h2 stored bf16-packed [N,20] uints.
__global__ __launch_bounds__(256) void gemm2_kernel(
    const float* __restrict__ helu, const float* __restrict__ W2,
    const float* __restrict__ a_s, const float* __restrict__ a_d,
    unsigned* __restrict__ h2b, float* __restrict__ als, float* __restrict__ ald, int n) {
    __shared__ float Wl[64 * 40];
    __shared__ float Al[4][16 * 64];
    for (int i = threadIdx.x; i < 64 * 40; i += 256) Wl[i] = W2[i];
    int w = threadIdx.x >> 6;
    int lane = threadIdx.x & 63;
    int node0 = (blockIdx.x * 4 + w) * 16;
    const float4* hv4 = (const float4*)helu;
    float4* Av4 = (float4*)Al[w];
#pragma unroll
    for (int i = 0; i < 4; ++i) {
        int f4 = i * 64 + lane;
        int g4 = node0 * 16 + f4;
        float4 v = (g4 < n * 16) ? hv4[g4] : make_float4(0.f, 0.f, 0.f, 0.f);
        Av4[f4] = v;
    }
    __syncthreads();
    bool act = lane < 40;
    int li = act ? lane : 0;
    float sums[16];
#pragma unroll
    for (int nd = 0; nd < 16; ++nd) sums[nd] = 0.f;
#pragma unroll 1
    for (int kc = 0; kc < 8; ++kc) {
        float wr[8];
#pragma unroll
        for (int i = 0; i < 8; ++i) wr[i] = Wl[(kc * 8 + i) * 40 + li];
#pragma unroll
        for (int nd = 0; nd < 16; ++nd) {
            float4 a = *(const float4*)&Al[w][nd * 64 + kc * 8];
            float4 b = *(const float4*)&Al[w][nd * 64 + kc * 8 + 4];
            float s = sums[nd];
            s = fmaf(wr[0], a.x, s); s = fmaf(wr[1], a.y, s);
            s = fmaf(wr[2], a.z, s); s = fmaf(wr[3], a.w, s);
            s = fmaf(wr[4], b.x, s); s = fmaf(wr[5], b.y, s);
            s = fmaf(wr[6], b.z, s); s = fmaf(wr[7], b.w, s);
            sums[nd] = s;
        }
    }
    float asv = act ? a_s[lane] : 0.f;
    float adv = act ? a_d[lane] : 0.f;
#pragma unroll
    for (int nd = 0; nd < 16; ++nd) {
        int node = node0 + nd;
        if (node >= n) break;
        float sum = sums[nd];
        float partner = __shfl_xor(sum, 1);
        if (act && (lane & 1) == 0) h2b[(size_t)node * 20 + (lane >> 1)] = pack_bf16x2(sum, partner);
        float vs = act ? sum * asv : 0.f;
        float vd = act ? sum * adv : 0.f;
#pragma unroll
        for (int i = 32; i >= 1; i >>= 1) { vs += __shfl_xor(vs, i); vd += __shfl_xor(vd, i); }
        if (lane == 0) { als[node] = vs; ald[node] = vd; }
    }
}

// agg2 (1 head, 40 ch) no-max softmax + half-wave edge split + log_softmax.
__global__ void agg2_kernel(const int* __restrict__ row_off, const int* __restrict__ deg,
                            const int2* __restrict__ csr_pair,
                            const unsigned* __restrict__ h2b, const float* __restrict__ als,
                            const float* __restrict__ ald, const float* __restrict__ b2,
                            float* __restrict__ out, int n) {
    int wid = (blockIdx.x << 2) + (threadIdx.x >> 6);
    int lane = threadIdx.x & 63;
    if (wid >= n) return;
    int half = lane >> 5;
    int l = lane & 31;
    bool act = l < 20;          // channel pairs 0..19
    int li = act ? l : 0;
    int off = row_off[wid];
    int cnt = deg[wid];
    float aldv = ald[wid];
    float dA = 0.f, dB = 0.f;
    float2 aA = {0.f, 0.f}, aB = {0.f, 0.f};
    for (int base = 0; base < cnt; base += 64) {
        int nb = min(64, cnt - base);
        int srcv = 0;
        if (lane < nb) srcv = csr_pair[off + base + lane].x;
        int j = 0;
        for (; j + 3 < nb; j += 4) {
            int sA0 = __builtin_amdgcn_readlane(srcv, j);
            int sA1 = __builtin_amdgcn_readlane(srcv, j + 1);
            int sB0 = __builtin_amdgcn_readlane(srcv, j + 2);
            int sB1 = __builtin_amdgcn_readlane(srcv, j + 3);
            int sA = half ? sA1 : sA0;
            int sB = half ? sB1 : sB0;
            float eA = als[sA] + aldv;
            float eB = als[sB] + aldv;
            eA = eA > 0.f ? eA : 0.2f * eA;
            eB = eB > 0.f ? eB : 0.2f * eB;
            float pA = __expf(eA);
            float pB = __expf(eB);
            unsigned uA = h2b[(size_t)sA * 20 + li];
            unsigned uB = h2b[(size_t)sB * 20 + li];
            dA += pA; dB += pB;
            aA.x = fmaf(pA, __uint_as_float(uA << 16), aA.x);
            aA.y = fmaf(pA, __uint_as_float(uA & 0xffff0000u), aA.y);
            aB.x = fmaf(pB, __uint_as_float(uB << 16), aB.x);
            aB.y = fmaf(pB, __uint_as_float(uB & 0xffff0000u), aB.y);
        }
        for (; j < nb; j += 2) {
            int s0 = __builtin_amdgcn_readlane(srcv, j);
            int s1 = (j + 1 < nb) ? __builtin_amdgcn_readlane(srcv, j + 1) : -1;
            int s = half ? s1 : s0;
            bool valid = s >= 0;
            int ss = valid ? s : 0;
            float e = als[ss] + aldv;
            e = e > 0.f ? e : 0.2f * e;
            float p = valid ? __expf(e) : 0.f;
            unsigned u = h2b[(size_t)ss * 20 + li];
            dA += p;
            aA.x = fmaf(p, __uint_as_float(u << 16), aA.x);
            aA.y = fmaf(p, __uint_as_float(u & 0xffff0000u), aA.y);
        }
    }
    float d = dA + dB;
    float2 accv = make_float2(aA.x + aB.x, aA.y + aB.y);
    d += __shfl_xor(d, 32);
    accv.x += __shfl_xor(accv.x, 32);
    accv.y += __shfl_xor(accv.y, 32);
    float inv = 1.f / d;
    bool live = (half == 0) && act;
    float ox = live ? fmaf(accv.x, inv, b2[2 * l]) : -1e30f;
    float oy = live ? fmaf(accv.y, inv, b2[2 * l + 1]) : -1e30f;
    float vv = fmaxf(ox, oy);
#pragma unroll
    for (int i = 16; i >= 1; i >>= 1) vv = fmaxf(vv, __shfl_xor(vv, i));
    float ex = live ? (__expf(ox - vv) + __expf(oy - vv)) : 0.f;
#pragma unroll
    for (int i = 16; i >= 1; i >>= 1) ex += __shfl_xor(ex, i);
    if (live) {
        float lse = vv + logf(ex);
        *(float2*)&out[(size_t)wid * 40 + 2 * l] = make_float2(ox - lse, oy - lse);
    }
}

extern "C" void kernel_launch(void* const* d_in, const int* in_sizes, int n_in,
                              void* d_out, int out_size, void* d_ws, size_t ws_size,
                              hipStream_t stream) {
    const float* x    = (const float*)d_in[0];
    const int*   ei   = (const int*)d_in[1];
    const float* t    = (const float*)d_in[2];
    const float* W1   = (const float*)d_in[3];
    const float* a_s1 = (const float*)d_in[4];
    const float* a_d1 = (const float*)d_in[5];
    const float* b1   = (const float*)d_in[6];
    const float* W2   = (const float*)d_in[7];
    const float* a_s2 = (const float*)d_in[8];
    const float* a_d2 = (const float*)d_in[9];
    const float* b2   = (const float*)d_in[10];
    float* out = (float*)d_out;

    const int N = in_sizes[0] / 128;
    const int E = in_sizes[1] / 2;

    char* w = (char*)d_ws;
    auto carve = [&](size_t bytes) {
        void* p = (void*)w;
        w += (bytes + 255) & ~(size_t)255;
        return p;
    };
    int*      deg      = (int*)carve((size_t)N * 4);
    int*      row_off  = (int*)carve((size_t)N * 4);
    int*      gcount   = (int*)carve(256);
    float*    dinv     = (float*)carve((size_t)N * 4);
    int*      epos     = (int*)carve((size_t)E * 4);
    int2*     csr_pair = (int2*)carve((size_t)(E + N) * 8);
    float*    coefs    = (float*)carve(11 * 128 * 4);
    float*    als1     = (float*)carve((size_t)N * 8 * 4);
    float*    ald1     = (float*)carve((size_t)N * 8 * 4);
    float*    als2     = (float*)carve((size_t)N * 4);
    float*    ald2     = (float*)carve((size_t)N * 4);
    float*    acc      = (float*)carve((size_t)N * 128 * 4);
    unsigned* h1b      = (unsigned*)carve((size_t)N * 32 * 4);  // bf16 [N,64]
    float*    helu     = (float*)carve((size_t)N * 64 * 4);
    unsigned* h2b      = (unsigned*)carve((size_t)N * 20 * 4);  // bf16 [N,40]

    // h buffers carved last; choose path by remaining scratch.
    size_t szh = (size_t)N * 64 * 4;                 // one bf16 h buffer (256-mult)
    size_t used = (size_t)(w - (char*)d_ws);
    size_t remain = (ws_size > used) ? ws_size - used : 0;
    bool pathA = remain >= 11 * szh;
    unsigned* hseq = (unsigned*)w;                   // h_0..h_10 contiguous (path A)
    size_t strideU = (size_t)N * 64;                 // uints per h buffer

    dim3 blk(256);
    int gN = (N + 255) / 256;
    int gE = (E + 255) / 256;
    int gEN = (E + N + 255) / 256;
    int gW = (N + 3) / 4;        // one wave per node, 4 waves/block
    int gT = (N + 63) / 64;      // wave per 16 nodes, 4 waves/block

    init_node_kernel<<<gN, blk, 0, stream>>>(deg, N);
    hipMemsetAsync(gcount, 0, 4, stream);
    edge_deg_kernel<<<gE, blk, 0, stream>>>(ei + E, deg, epos, E);
    alloc_kernel<<<gN, blk, 0, stream>>>(deg, dinv, row_off, gcount, N);
    scatter_kernel<<<gEN, blk, 0, stream>>>(ei, row_off, epos, dinv, csr_pair, E, N);
    coef_kernel<<<1, 128, 0, stream>>>(t, coefs);

    if (pathA) {
        init_diff_a_kernel<<<(N * 32 + 255) / 256, blk, 0, stream>>>(
            (const float4*)x, (uint2*)hseq, N * 32);
        for (int k = 1; k <= 10; ++k) {
            hop_a_kernel<<<gW, blk, 0, stream>>>(row_off, deg, csr_pair,
                                                 hseq + (size_t)(k - 1) * strideU,
                                                 hseq + (size_t)k * strideU, N);
        }
        combine_kernel<<<(N * 64 + 255) / 256, blk, 0, stream>>>(
            (const float2*)x, coefs, hseq, strideU, (float2*)acc, N * 64);
    } else {
        unsigned* hA = hseq;
        unsigned* hB = hseq + strideU;
        init_diff_b_kernel<<<(N * 32 + 255) / 256, blk, 0, stream>>>(
            (const float4*)x, coefs, (uint2*)hA, (float4*)acc, N * 32);
        unsigned* hc = hA;
        unsigned* hn = hB;
        for (int k = 1; k <= 10; ++k) {
            hop_b_kernel<<<gW, blk, 0, stream>>>(row_off, deg, csr_pair, hc, hn, (float2*)acc,
                                                 (const float2*)(coefs + k * 128), N,
                                                 k < 10 ? 1 : 0);
            unsigned* tmp = hc; hc = hn; hn = tmp;
        }
    }

    gemm1_kernel<<<gT, blk, 0, stream>>>(acc, W1, a_s1, a_d1, h1b, als1, ald1, N);
    agg1_kernel<<<gW, blk, 0, stream>>>(row_off, deg, csr_pair, h1b, als1, ald1, b1,
                                        (float2*)helu, N);
    gemm2_kernel<<<gT, blk, 0, stream>>>(helu, W2, a_s2, a_d2, h2b, als2, ald2, N);
    agg2_kernel<<<gW, blk, 0, stream>>>(row_off, deg, csr_pair, h2b, als2, ald2, b2, out, N);
}

// Round 16
// 1258.871 us; speedup vs baseline: 2.6251x; 1.0123x over previous
//
#include <hip/hip_runtime.h>
#include <hip/hip_bf16.h>

// ---------------------------------------------------------------------------
// GAT with heat-kernel diffusion preprocessing (GDC-style), MI355X.
// CSR build (atomic-free scatter) -> 10x pure-gather hops (bf16 ping-pong,
// NO acc traffic) + pairwise streaming acc accumulation -> tiled GEMM1
// (bf16 LDS staging, 32KB) -> no-max-softmax agg1 -> ELU -> GEMM2 -> agg2
// -> log_softmax.
// Round 13: round-12 evidence says ws_size < 409 MB so path A never ran.
// This layout needs ~173 MB (less than round 12 used). Hops shed the
// 102 MB/hop fp32 acc RMW; acc built by 5 streaming pair-kernels from the
// two live h buffers. gemm1 LDS 64->32 KB (bf16 Al+Wl) fixes its 17.6%
// occupancy (was latency-bound at 7% HBM, 38% VALU).
// ---------------------------------------------------------------------------

static __device__ __forceinline__ unsigned pack_bf16x2(float a, float b) {
    __hip_bfloat162 p(__float2bfloat16(a), __float2bfloat16(b));  // a in low 16
    return *reinterpret_cast<unsigned*>(&p);
}
static __device__ __forceinline__ float bf16lo(unsigned u) {
    return __uint_as_float(u << 16);
}
static __device__ __forceinline__ float bf16hi(unsigned u) {
    return __uint_as_float(u & 0xffff0000u);
}

__global__ void init_node_kernel(int* deg, int n) {
    int i = blockIdx.x * 256 + threadIdx.x;
    if (i < n) deg[i] = 1;  // slot 0 reserved for self loop
}

__global__ void edge_deg_kernel(const int* __restrict__ dst, int* deg, int* epos, int E) {
    int e = blockIdx.x * 256 + threadIdx.x;
    if (e < E) epos[e] = atomicAdd(&deg[dst[e]], 1);
}

__global__ void alloc_kernel(const int* __restrict__ deg, float* dinv,
                             int* row_off, int* gcount, int n) {
    int i = blockIdx.x * 256 + threadIdx.x;
    if (i >= n) return;
    int dg = deg[i];
    dinv[i] = rsqrtf((float)dg);
    row_off[i] = atomicAdd(gcount, dg);
}

// Atomic-free scatter: slot = row_off[dst] + epos[e]; self loop at slot 0.
__global__ void scatter_kernel(const int* __restrict__ ei, const int* __restrict__ row_off,
                               const int* __restrict__ epos, const float* __restrict__ dinv,
                               int2* __restrict__ csr_pair, int E, int n) {
    int e = blockIdx.x * 256 + threadIdx.x;
    if (e < E) {
        int s = ei[e], d = ei[E + e];
        csr_pair[row_off[d] + epos[e]] = make_int2(s, __float_as_int(dinv[s] * dinv[d]));
    } else if (e < E + n) {
        int i = e - E;
        float di = dinv[i];
        csr_pair[row_off[i]] = make_int2(i, __float_as_int(di * di));
    }
}

// coefs[k][c] = exp(-t_c) * t_c^k / k!
__global__ void coef_kernel(const float* __restrict__ t, float* coefs) {
    int c = threadIdx.x;  // 128 threads
    float tc = t[c];
    float v = expf(-tc);
    coefs[c] = v;
    for (int k = 1; k <= 10; ++k) { v *= tc / (float)k; coefs[k * 128 + c] = v; }
}

// h0 = bf16(x). No acc write (acc built by acc_first/acc_pair).
__global__ void init_diff_kernel(const float4* __restrict__ x4, uint2* __restrict__ h0,
                                 int total4) {
    int i = blockIdx.x * 256 + threadIdx.x;
    if (i >= total4) return;
    float4 xv = x4[i];
    h0[i] = make_uint2(pack_bf16x2(xv.x, xv.y), pack_bf16x2(xv.z, xv.w));
}

// Gather: s = (A_hat h)[node], 2 channels/lane, 8 loads in flight.
static __device__ __forceinline__ float2 gather_row(
    const int* __restrict__ row_off, const int* __restrict__ deg,
    const int2* __restrict__ csr_pair, const unsigned* __restrict__ h,
    int wid, int lane) {
    int off = row_off[wid];
    int cnt = deg[wid];
    float2 a0 = {0.f, 0.f}, a1 = {0.f, 0.f}, a2 = {0.f, 0.f}, a3 = {0.f, 0.f};
    for (int base = 0; base < cnt; base += 64) {
        int nb = min(64, cnt - base);
        int2 p = {0, 0};
        if (lane < nb) p = csr_pair[off + base + lane];
        int tt = 0;
        for (; tt + 7 < nb; tt += 8) {
            int s0 = __builtin_amdgcn_readlane(p.x, tt);
            int s1 = __builtin_amdgcn_readlane(p.x, tt + 1);
            int s2 = __builtin_amdgcn_readlane(p.x, tt + 2);
            int s3 = __builtin_amdgcn_readlane(p.x, tt + 3);
            int s4 = __builtin_amdgcn_readlane(p.x, tt + 4);
            int s5 = __builtin_amdgcn_readlane(p.x, tt + 5);
            int s6 = __builtin_amdgcn_readlane(p.x, tt + 6);
            int s7 = __builtin_amdgcn_readlane(p.x, tt + 7);
            float w0 = __int_as_float(__builtin_amdgcn_readlane(p.y, tt));
            float w1 = __int_as_float(__builtin_amdgcn_readlane(p.y, tt + 1));
            float w2 = __int_as_float(__builtin_amdgcn_readlane(p.y, tt + 2));
            float w3 = __int_as_float(__builtin_amdgcn_readlane(p.y, tt + 3));
            float w4 = __int_as_float(__builtin_amdgcn_readlane(p.y, tt + 4));
            float w5 = __int_as_float(__builtin_amdgcn_readlane(p.y, tt + 5));
            float w6 = __int_as_float(__builtin_amdgcn_readlane(p.y, tt + 6));
            float w7 = __int_as_float(__builtin_amdgcn_readlane(p.y, tt + 7));
            unsigned u0 = h[(size_t)s0 * 64 + lane];
            unsigned u1 = h[(size_t)s1 * 64 + lane];
            unsigned u2 = h[(size_t)s2 * 64 + lane];
            unsigned u3 = h[(size_t)s3 * 64 + lane];
            unsigned u4 = h[(size_t)s4 * 64 + lane];
            unsigned u5 = h[(size_t)s5 * 64 + lane];
            unsigned u6 = h[(size_t)s6 * 64 + lane];
            unsigned u7 = h[(size_t)s7 * 64 + lane];
            a0.x = fmaf(w0, bf16lo(u0), a0.x); a0.y = fmaf(w0, bf16hi(u0), a0.y);
            a1.x = fmaf(w1, bf16lo(u1), a1.x); a1.y = fmaf(w1, bf16hi(u1), a1.y);
            a2.x = fmaf(w2, bf16lo(u2), a2.x); a2.y = fmaf(w2, bf16hi(u2), a2.y);
            a3.x = fmaf(w3, bf16lo(u3), a3.x); a3.y = fmaf(w3, bf16hi(u3), a3.y);
            a0.x = fmaf(w4, bf16lo(u4), a0.x); a0.y = fmaf(w4, bf16hi(u4), a0.y);
            a1.x = fmaf(w5, bf16lo(u5), a1.x); a1.y = fmaf(w5, bf16hi(u5), a1.y);
            a2.x = fmaf(w6, bf16lo(u6), a2.x); a2.y = fmaf(w6, bf16hi(u6), a2.y);
            a3.x = fmaf(w7, bf16lo(u7), a3.x); a3.y = fmaf(w7, bf16hi(u7), a3.y);
        }
        for (; tt < nb; ++tt) {
            int s = __builtin_amdgcn_readlane(p.x, tt);
            float w = __int_as_float(__builtin_amdgcn_readlane(p.y, tt));
            unsigned u = h[(size_t)s * 64 + lane];
            a0.x = fmaf(w, bf16lo(u), a0.x); a0.y = fmaf(w, bf16hi(u), a0.y);
        }
    }
    float2 s;
    s.x = (a0.x + a1.x) + (a2.x + a3.x);
    s.y = (a0.y + a1.y) + (a2.y + a3.y);
    return s;
}

// Pure hop: h_out = bf16(A_hat h_prev). No acc traffic.
__global__ void hop_kernel(const int* __restrict__ row_off, const int* __restrict__ deg,
                           const int2* __restrict__ csr_pair,
                           const unsigned* __restrict__ h_prev, unsigned* __restrict__ h_out,
                           int n) {
    int wid = (blockIdx.x << 2) + (threadIdx.x >> 6);
    int lane = threadIdx.x & 63;
    if (wid >= n) return;
    float2 s = gather_row(row_off, deg, csr_pair, h_prev, wid, lane);
    h_out[(size_t)wid * 64 + lane] = pack_bf16x2(s.x, s.y);
}

// acc = c0*x + cA*hA + cB*hB  (first pair; x read in full precision)
__global__ void acc_first_kernel(const float4* __restrict__ x4,
                                 const uint2* __restrict__ hA, const uint2* __restrict__ hB,
                                 const float* __restrict__ coefs,
                                 float4* __restrict__ acc4, int total4) {
    int i = blockIdx.x * 256 + threadIdx.x;
    if (i >= total4) return;
    int c4 = (i & 31) * 4;
    const float4 c0 = *(const float4*)&coefs[c4];
    const float4 cA = *(const float4*)&coefs[128 + c4];
    const float4 cB = *(const float4*)&coefs[256 + c4];
    float4 xv = x4[i];
    uint2 ua = hA[i];
    uint2 ub = hB[i];
    float4 a;
    a.x = c0.x * xv.x + cA.x * bf16lo(ua.x) + cB.x * bf16lo(ub.x);
    a.y = c0.y * xv.y + cA.y * bf16hi(ua.x) + cB.y * bf16hi(ub.x);
    a.z = c0.z * xv.z + cA.z * bf16lo(ua.y) + cB.z * bf16lo(ub.y);
    a.w = c0.w * xv.w + cA.w * bf16hi(ua.y) + cB.w * bf16hi(ub.y);
    acc4[i] = a;
}

// acc += cA*hA + cB*hB  (streaming RMW every 2 hops)
__global__ void acc_pair_kernel(const uint2* __restrict__ hA, const uint2* __restrict__ hB,
                                const float* __restrict__ coefA, const float* __restrict__ coefB,
                                float4* __restrict__ acc4, int total4) {
    int i = blockIdx.x * 256 + threadIdx.x;
    if (i >= total4) return;
    int c4 = (i & 31) * 4;
    const float4 cA = *(const float4*)&coefA[c4];
    const float4 cB = *(const float4*)&coefB[c4];
    uint2 ua = hA[i];
    uint2 ub = hB[i];
    float4 a = acc4[i];
    a.x += cA.x * bf16lo(ua.x) + cB.x * bf16lo(ub.x);
    a.y += cA.y * bf16hi(ua.x) + cB.y * bf16hi(ub.x);
    a.z += cA.z * bf16lo(ua.y) + cB.z * bf16lo(ub.y);
    a.w += cA.w * bf16hi(ua.y) + cB.w * bf16hi(ub.y);
    acc4[i] = a;
}

// h1 = acc @ W1 (128x64) tiled; bf16 LDS staging (Al 16KB + Wl 16KB = 32KB ->
// 5 blocks/CU; round-12 fp32 version was 64KB -> 17.6% occupancy).
// kc loop unroll(1): full unroll spilled to scratch (round-4 regression).
__global__ __launch_bounds__(256) void gemm1_kernel(
    const float* __restrict__ acc, const float* __restrict__ W1,
    const float* __restrict__ a_s, const float* __restrict__ a_d,
    unsigned* __restrict__ h1b, float* __restrict__ als, float* __restrict__ ald, int n) {
    __shared__ unsigned short Wl16[128 * 64];  // bf16 weights, 16 KB
    __shared__ unsigned Al[4][16 * 64];        // bf16x2-packed acc rows, 16 KB
    for (int i = threadIdx.x; i < 128 * 64; i += 256)
        Wl16[i] = (unsigned short)(pack_bf16x2(W1[i], 0.f) & 0xffffu);
    int w = threadIdx.x >> 6;
    int lane = threadIdx.x & 63;
    int node0 = (blockIdx.x * 4 + w) * 16;
    const float2* acc2 = (const float2*)acc;
#pragma unroll
    for (int i = 0; i < 16; ++i) {
        int node = node0 + i;
        float2 v = (node < n) ? acc2[(size_t)node * 64 + lane] : make_float2(0.f, 0.f);
        Al[w][i * 64 + lane] = pack_bf16x2(v.x, v.y);
    }
    __syncthreads();
    float sums[16];
#pragma unroll
    for (int nd = 0; nd < 16; ++nd) sums[nd] = 0.f;
#pragma unroll 1
    for (int kc = 0; kc < 16; ++kc) {
        float wr[8];
#pragma unroll
        for (int i = 0; i < 8; ++i)
            wr[i] = __uint_as_float((unsigned)Wl16[(kc * 8 + i) * 64 + lane] << 16);
#pragma unroll
        for (int nd = 0; nd < 16; ++nd) {
            uint4 u = *(const uint4*)&Al[w][nd * 64 + kc * 4];
            float s = sums[nd];
            s = fmaf(wr[0], bf16lo(u.x), s); s = fmaf(wr[1], bf16hi(u.x), s);
            s = fmaf(wr[2], bf16lo(u.y), s); s = fmaf(wr[3], bf16hi(u.y), s);
            s = fmaf(wr[4], bf16lo(u.z), s); s = fmaf(wr[5], bf16hi(u.z), s);
            s = fmaf(wr[6], bf16lo(u.w), s); s = fmaf(wr[7], bf16hi(u.w), s);
            sums[nd] = s;
        }
    }
    float asv = a_s[lane], adv = a_d[lane];
#pragma unroll
    for (int nd = 0; nd < 16; ++nd) {
        int node = node0 + nd;
        if (node >= n) break;
        float sum = sums[nd];
        float partner = __shfl_xor(sum, 1);
        if ((lane & 1) == 0) h1b[(size_t)node * 32 + (lane >> 1)] = pack_bf16x2(sum, partner);
        float vs = sum * asv;
        float vd = sum * adv;
        vs += __shfl_xor(vs, 1); vs += __shfl_xor(vs, 2); vs += __shfl_xor(vs, 4);
        vd += __shfl_xor(vd, 1); vd += __shfl_xor(vd, 2); vd += __shfl_xor(vd, 4);
        if ((lane & 7) == 0) {
            als[(size_t)node * 8 + (lane >> 3)] = vs;
            ald[(size_t)node * 8 + (lane >> 3)] = vd;
        }
    }
}

// agg1: softmax agg without max subtraction (shift-invariant; logits O(1)).
// Half-wave edge parallelism; channel pair (2l,2l+1) bf16-packed per lane.
__global__ void agg1_kernel(const int* __restrict__ row_off, const int* __restrict__ deg,
                            const int2* __restrict__ csr_pair,
                            const unsigned* __restrict__ h1b, const float* __restrict__ als,
                            const float* __restrict__ ald, const float* __restrict__ b1,
                            float2* __restrict__ helu2, int n) {
    int wid = (blockIdx.x << 2) + (threadIdx.x >> 6);
    int lane = threadIdx.x & 63;
    if (wid >= n) return;
    int half = lane >> 5;
    int l = lane & 31;          // channel pair index
    int head = l >> 2;          // (2l)>>3
    int off = row_off[wid];
    int cnt = deg[wid];
    float aldv = ald[(size_t)wid * 8 + head];
    float dA = 0.f, dB = 0.f;
    float2 aA = {0.f, 0.f}, aB = {0.f, 0.f};
    for (int base = 0; base < cnt; base += 64) {
        int nb = min(64, cnt - base);
        int srcv = 0;
        if (lane < nb) srcv = csr_pair[off + base + lane].x;
        int j = 0;
        for (; j + 3 < nb; j += 4) {
            int sA0 = __builtin_amdgcn_readlane(srcv, j);
            int sA1 = __builtin_amdgcn_readlane(srcv, j + 1);
            int sB0 = __builtin_amdgcn_readlane(srcv, j + 2);
            int sB1 = __builtin_amdgcn_readlane(srcv, j + 3);
            int sA = half ? sA1 : sA0;
            int sB = half ? sB1 : sB0;
            float eA = als[(size_t)sA * 8 + head] + aldv;
            float eB = als[(size_t)sB * 8 + head] + aldv;
            eA = eA > 0.f ? eA : 0.2f * eA;
            eB = eB > 0.f ? eB : 0.2f * eB;
            float pA = __expf(eA);
            float pB = __expf(eB);
            unsigned uA = h1b[(size_t)sA * 32 + l];
            unsigned uB = h1b[(size_t)sB * 32 + l];
            dA += pA; dB += pB;
            aA.x = fmaf(pA, bf16lo(uA), aA.x);
            aA.y = fmaf(pA, bf16hi(uA), aA.y);
            aB.x = fmaf(pB, bf16lo(uB), aB.x);
            aB.y = fmaf(pB, bf16hi(uB), aB.y);
        }
        for (; j < nb; j += 2) {
            int s0 = __builtin_amdgcn_readlane(srcv, j);
            int s1 = (j + 1 < nb) ? __builtin_amdgcn_readlane(srcv, j + 1) : -1;
            int s = half ? s1 : s0;
            bool valid = s >= 0;
            int ss = valid ? s : 0;
            float e = als[(size_t)ss * 8 + head] + aldv;
            e = e > 0.f ? e : 0.2f * e;
            float p = valid ? __expf(e) : 0.f;
            unsigned u = h1b[(size_t)ss * 32 + l];
            dA += p;
            aA.x = fmaf(p, bf16lo(u), aA.x);
            aA.y = fmaf(p, bf16hi(u), aA.y);
        }
    }
    float d = dA + dB;
    float2 accv = make_float2(aA.x + aB.x, aA.y + aB.y);
    d += __shfl_xor(d, 32);
    accv.x += __shfl_xor(accv.x, 32);
    accv.y += __shfl_xor(accv.y, 32);
    if (half == 0) {
        float inv = 1.f / d;   // d >= exp(self-loop logit) > 0
        float ox = fmaf(accv.x, inv, b1[2 * l]);
        float oy = fmaf(accv.y, inv, b1[2 * l + 1]);
        ox = ox > 0.f ? ox : expm1f(ox);  // ELU
        oy = oy > 0.f ? oy : expm1f(oy);
        helu2[(size_t)wid * 32 + l] = make_float2(ox, oy);
    }
}

// h2 = helu @ W2 (64x40) tiled; h2 stored bf16-packed [N,20] uints.
__global__ __launch_bounds__(256) void gemm2_kernel(
    const float* __restrict__ helu, const float* __restrict__ W2,
    const float* __restrict__ a_s, const float* __restrict__ a_d,
    unsigned* __restrict__ h2b, float* __restrict__ als, float* __restrict__ ald, int n) {
    __shared__ float Wl[64 * 40];
    __shared__ float Al[4][16 * 64];
    for (int i = threadIdx.x; i < 64 * 40; i += 256) Wl[i] = W2[i];
    int w = threadIdx.x >> 6;
    int lane = threadIdx.x & 63;
    int node0 = (blockIdx.x * 4 + w) * 16;
    const float4* hv4 = (const float4*)helu;
    float4* Av4 = (float4*)Al[w];
#pragma unroll
    for (int i = 0; i < 4; ++i) {
        int f4 = i * 64 + lane;
        int g4 = node0 * 16 + f4;
        float4 v = (g4 < n * 16) ? hv4[g4] : make_float4(0.f, 0.f, 0.f, 0.f);
        Av4[f4] = v;
    }
    __syncthreads();
    bool act = lane < 40;
    int li = act ? lane : 0;
    float sums[16];
#pragma unroll
    for (int nd = 0; nd < 16; ++nd) sums[nd] = 0.f;
#pragma unroll 1
    for (int kc = 0; kc < 8; ++kc) {
        float wr[8];
#pragma unroll
        for (int i = 0; i < 8; ++i) wr[i] = Wl[(kc * 8 + i) * 40 + li];
#pragma unroll
        for (int nd = 0; nd < 16; ++nd) {
            float4 a = *(const float4*)&Al[w][nd * 64 + kc * 8];
            float4 b = *(const float4*)&Al[w][nd * 64 + kc * 8 + 4];
            float s = sums[nd];
            s = fmaf(wr[0], a.x, s); s = fmaf(wr[1], a.y, s);
            s = fmaf(wr[2], a.z, s); s = fmaf(wr[3], a.w, s);
            s = fmaf(wr[4], b.x, s); s = fmaf(wr[5], b.y, s);
            s = fmaf(wr[6], b.z, s); s = fmaf(wr[7], b.w, s);
            sums[nd] = s;
        }
    }
    float asv = act ? a_s[lane] : 0.f;
    float adv = act ? a_d[lane] : 0.f;
#pragma unroll
    for (int nd = 0; nd < 16; ++nd) {
        int node = node0 + nd;
        if (node >= n) break;
        float sum = sums[nd];
        float partner = __shfl_xor(sum, 1);
        if (act && (lane & 1) == 0) h2b[(size_t)node * 20 + (lane >> 1)] = pack_bf16x2(sum, partner);
        float vs = act ? sum * asv : 0.f;
        float vd = act ? sum * adv : 0.f;
#pragma unroll
        for (int i = 32; i >= 1; i >>= 1) { vs += __shfl_xor(vs, i); vd += __shfl_xor(vd, i); }
        if (lane == 0) { als[node] = vs; ald[node] = vd; }
    }
}

// agg2 (1 head, 40 ch) no-max softmax + half-wave edge split + log_softmax.
__global__ void agg2_kernel(const int* __restrict__ row_off, const int* __restrict__ deg,
                            const int2* __restrict__ csr_pair,
                            const unsigned* __restrict__ h2b, const float* __restrict__ als,
                            const float* __restrict__ ald, const float* __restrict__ b2,
                            float* __restrict__ out, int n) {
    int wid = (blockIdx.x << 2) + (threadIdx.x >> 6);
    int lane = threadIdx.x & 63;
    if (wid >= n) return;
    int half = lane >> 5;
    int l = lane & 31;
    bool act = l < 20;          // channel pairs 0..19
    int li = act ? l : 0;
    int off = row_off[wid];
    int cnt = deg[wid];
    float aldv = ald[wid];
    float dA = 0.f, dB = 0.f;
    float2 aA = {0.f, 0.f}, aB = {0.f, 0.f};
    for (int base = 0; base < cnt; base += 64) {
        int nb = min(64, cnt - base);
        int srcv = 0;
        if (lane < nb) srcv = csr_pair[off + base + lane].x;
        int j = 0;
        for (; j + 3 < nb; j += 4) {
            int sA0 = __builtin_amdgcn_readlane(srcv, j);
            int sA1 = __builtin_amdgcn_readlane(srcv, j + 1);
            int sB0 = __builtin_amdgcn_readlane(srcv, j + 2);
            int sB1 = __builtin_amdgcn_readlane(srcv, j + 3);
            int sA = half ? sA1 : sA0;
            int sB = half ? sB1 : sB0;
            float eA = als[sA] + aldv;
            float eB = als[sB] + aldv;
            eA = eA > 0.f ? eA : 0.2f * eA;
            eB = eB > 0.f ? eB : 0.2f * eB;
            float pA = __expf(eA);
            float pB = __expf(eB);
            unsigned uA = h2b[(size_t)sA * 20 + li];
            unsigned uB = h2b[(size_t)sB * 20 + li];
            dA += pA; dB += pB;
            aA.x = fmaf(pA, bf16lo(uA), aA.x);
            aA.y = fmaf(pA, bf16hi(uA), aA.y);
            aB.x = fmaf(pB, bf16lo(uB), aB.x);
            aB.y = fmaf(pB, bf16hi(uB), aB.y);
        }
        for (; j < nb; j += 2) {
            int s0 = __builtin_amdgcn_readlane(srcv, j);
            int s1 = (j + 1 < nb) ? __builtin_amdgcn_readlane(srcv, j + 1) : -1;
            int s = half ? s1 : s0;
            bool valid = s >= 0;
            int ss = valid ? s : 0;
            float e = als[ss] + aldv;
            e = e > 0.f ? e : 0.2f * e;
            float p = valid ? __expf(e) : 0.f;
            unsigned u = h2b[(size_t)ss * 20 + li];
            dA += p;
            aA.x = fmaf(p, bf16lo(u), aA.x);
            aA.y = fmaf(p, bf16hi(u), aA.y);
        }
    }
    float d = dA + dB;
    float2 accv = make_float2(aA.x + aB.x, aA.y + aB.y);
    d += __shfl_xor(d, 32);
    accv.x += __shfl_xor(accv.x, 32);
    accv.y += __shfl_xor(accv.y, 32);
    float inv = 1.f / d;
    bool live = (half == 0) && act;
    float ox = live ? fmaf(accv.x, inv, b2[2 * l]) : -1e30f;
    float oy = live ? fmaf(accv.y, inv, b2[2 * l + 1]) : -1e30f;
    float vv = fmaxf(ox, oy);
#pragma unroll
    for (int i = 16; i >= 1; i >>= 1) vv = fmaxf(vv, __shfl_xor(vv, i));
    float ex = live ? (__expf(ox - vv) + __expf(oy - vv)) : 0.f;
#pragma unroll
    for (int i = 16; i >= 1; i >>= 1) ex += __shfl_xor(ex, i);
    if (live) {
        float lse = vv + logf(ex);
        *(float2*)&out[(size_t)wid * 40 + 2 * l] = make_float2(ox - lse, oy - lse);
    }
}

extern "C" void kernel_launch(void* const* d_in, const int* in_sizes, int n_in,
                              void* d_out, int out_size, void* d_ws, size_t ws_size,
                              hipStream_t stream) {
    const float* x    = (const float*)d_in[0];
    const int*   ei   = (const int*)d_in[1];
    const float* t    = (const float*)d_in[2];
    const float* W1   = (const float*)d_in[3];
    const float* a_s1 = (const float*)d_in[4];
    const float* a_d1 = (const float*)d_in[5];
    const float* b1   = (const float*)d_in[6];
    const float* W2   = (const float*)d_in[7];
    const float* a_s2 = (const float*)d_in[8];
    const float* a_d2 = (const float*)d_in[9];
    const float* b2   = (const float*)d_in[10];
    float* out = (float*)d_out;

    const int N = in_sizes[0] / 128;
    const int E = in_sizes[1] / 2;

    char* w = (char*)d_ws;
    auto carve = [&](size_t bytes) {
        void* p = (void*)w;
        w += (bytes + 255) & ~(size_t)255;
        return p;
    };
    int*      deg      = (int*)carve((size_t)N * 4);
    int*      row_off  = (int*)carve((size_t)N * 4);
    int*      gcount   = (int*)carve(256);
    float*    dinv     = (float*)carve((size_t)N * 4);
    int*      epos     = (int*)carve((size_t)E * 4);
    int2*     csr_pair = (int2*)carve((size_t)(E + N) * 8);
    float*    coefs    = (float*)carve(11 * 128 * 4);
    float*    als1     = (float*)carve((size_t)N * 8 * 4);
    float*    ald1     = (float*)carve((size_t)N * 8 * 4);
    float*    als2     = (float*)carve((size_t)N * 4);
    float*    ald2     = (float*)carve((size_t)N * 4);
    float*    acc      = (float*)carve((size_t)N * 128 * 4);
    unsigned* hA       = (unsigned*)carve((size_t)N * 64 * 4);  // bf16x2 per uint
    unsigned* hB       = (unsigned*)carve((size_t)N * 64 * 4);
    unsigned* h1b      = (unsigned*)carve((size_t)N * 32 * 4);  // bf16 [N,64]
    float*    helu     = (float*)carve((size_t)N * 64 * 4);
    unsigned* h2b      = (unsigned*)carve((size_t)N * 20 * 4);  // bf16 [N,40]

    dim3 blk(256);
    int gN = (N + 255) / 256;
    int gE = (E + 255) / 256;
    int gEN = (E + N + 255) / 256;
    int gW = (N + 3) / 4;        // one wave per node, 4 waves/block
    int gT = (N + 63) / 64;      // wave per 16 nodes, 4 waves/block
    int gS = (N * 32 + 255) / 256;  // streaming float4/uint2 grids

    init_node_kernel<<<gN, blk, 0, stream>>>(deg, N);
    hipMemsetAsync(gcount, 0, 4, stream);
    edge_deg_kernel<<<gE, blk, 0, stream>>>(ei + E, deg, epos, E);
    alloc_kernel<<<gN, blk, 0, stream>>>(deg, dinv, row_off, gcount, N);
    scatter_kernel<<<gEN, blk, 0, stream>>>(ei, row_off, epos, dinv, csr_pair, E, N);
    coef_kernel<<<1, 128, 0, stream>>>(t, coefs);
    init_diff_kernel<<<gS, blk, 0, stream>>>((const float4*)x, (uint2*)hA, N * 32);

    // hops 1..10; h_k lives in hB for odd k, hA for even k.
    // acc built pairwise: after hop2 acc = c0 x + c1 h1 + c2 h2; then += per pair.
    unsigned* hc = hA;
    unsigned* hn = hB;
    for (int k = 1; k <= 10; ++k) {
        hop_kernel<<<gW, blk, 0, stream>>>(row_off, deg, csr_pair, hc, hn, N);
        unsigned* tmp = hc; hc = hn; hn = tmp;
        if (k == 2) {
            acc_first_kernel<<<gS, blk, 0, stream>>>(
                (const float4*)x, (const uint2*)hB, (const uint2*)hA, coefs,
                (float4*)acc, N * 32);
        } else if ((k & 1) == 0) {
            acc_pair_kernel<<<gS, blk, 0, stream>>>(
                (const uint2*)hB, (const uint2*)hA,
                coefs + (size_t)(k - 1) * 128, coefs + (size_t)k * 128,
                (float4*)acc, N * 32);
        }
    }

    gemm1_kernel<<<gT, blk, 0, stream>>>(acc, W1, a_s1, a_d1, h1b, als1, ald1, N);
    agg1_kernel<<<gW, blk, 0, stream>>>(row_off, deg, csr_pair, h1b, als1, ald1, b1,
                                        (float2*)helu, N);
    gemm2_kernel<<<gT, blk, 0, stream>>>(helu, W2, a_s2, a_d2, h2b, als2, ald2, N);
    agg2_kernel<<<gW, blk, 0, stream>>>(row_off, deg, csr_pair, h2b, als2, ald2, b2, out, N);
}

// Round 17
// 1216.548 us; speedup vs baseline: 2.7164x; 1.0348x over previous
//
#include <hip/hip_runtime.h>
#include <hip/hip_bf16.h>

// ---------------------------------------------------------------------------
// GAT with heat-kernel diffusion preprocessing (GDC-style), MI355X.
// CSR build (atomic-free scatter) -> 10x gather hops (bf16 ping-pong; even
// hops fuse the pairwise fp32 acc update, killing the 5 standalone acc
// kernels) -> tiled GEMM1 (bf16 LDS, 32KB) -> no-max-softmax agg1 -> ELU ->
// GEMM2 -> agg2 (per-lane exp precompute, p broadcast via readlane) ->
// log_softmax.
// Round 17: agg2 was VALU-bound (73% busy) from 32x-redundant exp per edge;
// precompute p per lane, broadcast. Fuse acc pairs into even hops.
// ---------------------------------------------------------------------------

static __device__ __forceinline__ unsigned pack_bf16x2(float a, float b) {
    __hip_bfloat162 p(__float2bfloat16(a), __float2bfloat16(b));  // a in low 16
    return *reinterpret_cast<unsigned*>(&p);
}
static __device__ __forceinline__ float bf16lo(unsigned u) {
    return __uint_as_float(u << 16);
}
static __device__ __forceinline__ float bf16hi(unsigned u) {
    return __uint_as_float(u & 0xffff0000u);
}
static __device__ __forceinline__ float readlane_f(float v, int l) {
    return __int_as_float(__builtin_amdgcn_readlane(__float_as_int(v), l));
}

__global__ void init_node_kernel(int* deg, int n) {
    int i = blockIdx.x * 256 + threadIdx.x;
    if (i < n) deg[i] = 1;  // slot 0 reserved for self loop
}

__global__ void edge_deg_kernel(const int* __restrict__ dst, int* deg, int* epos, int E) {
    int e = blockIdx.x * 256 + threadIdx.x;
    if (e < E) epos[e] = atomicAdd(&deg[dst[e]], 1);
}

__global__ void alloc_kernel(const int* __restrict__ deg, float* dinv,
                             int* row_off, int* gcount, int n) {
    int i = blockIdx.x * 256 + threadIdx.x;
    if (i >= n) return;
    int dg = deg[i];
    dinv[i] = rsqrtf((float)dg);
    row_off[i] = atomicAdd(gcount, dg);
}

// Atomic-free scatter: slot = row_off[dst] + epos[e]; self loop at slot 0.
__global__ void scatter_kernel(const int* __restrict__ ei, const int* __restrict__ row_off,
                               const int* __restrict__ epos, const float* __restrict__ dinv,
                               int2* __restrict__ csr_pair, int E, int n) {
    int e = blockIdx.x * 256 + threadIdx.x;
    if (e < E) {
        int s = ei[e], d = ei[E + e];
        csr_pair[row_off[d] + epos[e]] = make_int2(s, __float_as_int(dinv[s] * dinv[d]));
    } else if (e < E + n) {
        int i = e - E;
        float di = dinv[i];
        csr_pair[row_off[i]] = make_int2(i, __float_as_int(di * di));
    }
}

// coefs[k][c] = exp(-t_c) * t_c^k / k!
__global__ void coef_kernel(const float* __restrict__ t, float* coefs) {
    int c = threadIdx.x;  // 128 threads
    float tc = t[c];
    float v = expf(-tc);
    coefs[c] = v;
    for (int k = 1; k <= 10; ++k) { v *= tc / (float)k; coefs[k * 128 + c] = v; }
}

// h0 = bf16(x). acc is seeded by the first fused hop (k=2).
__global__ void init_diff_kernel(const float4* __restrict__ x4, uint2* __restrict__ h0,
                                 int total4) {
    int i = blockIdx.x * 256 + threadIdx.x;
    if (i >= total4) return;
    float4 xv = x4[i];
    h0[i] = make_uint2(pack_bf16x2(xv.x, xv.y), pack_bf16x2(xv.z, xv.w));
}

// Gather: s = (A_hat h)[node], 2 channels/lane, 8 loads in flight.
static __device__ __forceinline__ float2 gather_row(
    const int* __restrict__ row_off, const int* __restrict__ deg,
    const int2* __restrict__ csr_pair, const unsigned* __restrict__ h,
    int wid, int lane) {
    int off = row_off[wid];
    int cnt = deg[wid];
    float2 a0 = {0.f, 0.f}, a1 = {0.f, 0.f}, a2 = {0.f, 0.f}, a3 = {0.f, 0.f};
    for (int base = 0; base < cnt; base += 64) {
        int nb = min(64, cnt - base);
        int2 p = {0, 0};
        if (lane < nb) p = csr_pair[off + base + lane];
        int tt = 0;
        for (; tt + 7 < nb; tt += 8) {
            int s0 = __builtin_amdgcn_readlane(p.x, tt);
            int s1 = __builtin_amdgcn_readlane(p.x, tt + 1);
            int s2 = __builtin_amdgcn_readlane(p.x, tt + 2);
            int s3 = __builtin_amdgcn_readlane(p.x, tt + 3);
            int s4 = __builtin_amdgcn_readlane(p.x, tt + 4);
            int s5 = __builtin_amdgcn_readlane(p.x, tt + 5);
            int s6 = __builtin_amdgcn_readlane(p.x, tt + 6);
            int s7 = __builtin_amdgcn_readlane(p.x, tt + 7);
            float w0 = __int_as_float(__builtin_amdgcn_readlane(p.y, tt));
            float w1 = __int_as_float(__builtin_amdgcn_readlane(p.y, tt + 1));
            float w2 = __int_as_float(__builtin_amdgcn_readlane(p.y, tt + 2));
            float w3 = __int_as_float(__builtin_amdgcn_readlane(p.y, tt + 3));
            float w4 = __int_as_float(__builtin_amdgcn_readlane(p.y, tt + 4));
            float w5 = __int_as_float(__builtin_amdgcn_readlane(p.y, tt + 5));
            float w6 = __int_as_float(__builtin_amdgcn_readlane(p.y, tt + 6));
            float w7 = __int_as_float(__builtin_amdgcn_readlane(p.y, tt + 7));
            unsigned u0 = h[(size_t)s0 * 64 + lane];
            unsigned u1 = h[(size_t)s1 * 64 + lane];
            unsigned u2 = h[(size_t)s2 * 64 + lane];
            unsigned u3 = h[(size_t)s3 * 64 + lane];
            unsigned u4 = h[(size_t)s4 * 64 + lane];
            unsigned u5 = h[(size_t)s5 * 64 + lane];
            unsigned u6 = h[(size_t)s6 * 64 + lane];
            unsigned u7 = h[(size_t)s7 * 64 + lane];
            a0.x = fmaf(w0, bf16lo(u0), a0.x); a0.y = fmaf(w0, bf16hi(u0), a0.y);
            a1.x = fmaf(w1, bf16lo(u1), a1.x); a1.y = fmaf(w1, bf16hi(u1), a1.y);
            a2.x = fmaf(w2, bf16lo(u2), a2.x); a2.y = fmaf(w2, bf16hi(u2), a2.y);
            a3.x = fmaf(w3, bf16lo(u3), a3.x); a3.y = fmaf(w3, bf16hi(u3), a3.y);
            a0.x = fmaf(w4, bf16lo(u4), a0.x); a0.y = fmaf(w4, bf16hi(u4), a0.y);
            a1.x = fmaf(w5, bf16lo(u5), a1.x); a1.y = fmaf(w5, bf16hi(u5), a1.y);
            a2.x = fmaf(w6, bf16lo(u6), a2.x); a2.y = fmaf(w6, bf16hi(u6), a2.y);
            a3.x = fmaf(w7, bf16lo(u7), a3.x); a3.y = fmaf(w7, bf16hi(u7), a3.y);
        }
        for (; tt < nb; ++tt) {
            int s = __builtin_amdgcn_readlane(p.x, tt);
            float w = __int_as_float(__builtin_amdgcn_readlane(p.y, tt));
            unsigned u = h[(size_t)s * 64 + lane];
            a0.x = fmaf(w, bf16lo(u), a0.x); a0.y = fmaf(w, bf16hi(u), a0.y);
        }
    }
    float2 s;
    s.x = (a0.x + a1.x) + (a2.x + a3.x);
    s.y = (a0.y + a1.y) + (a2.y + a3.y);
    return s;
}

// Pure hop (odd k): h_out = bf16(A_hat h_prev). No acc traffic.
__global__ void hop_kernel(const int* __restrict__ row_off, const int* __restrict__ deg,
                           const int2* __restrict__ csr_pair,
                           const unsigned* __restrict__ h_prev, unsigned* __restrict__ h_out,
                           int n) {
    int wid = (blockIdx.x << 2) + (threadIdx.x >> 6);
    int lane = threadIdx.x & 63;
    if (wid >= n) return;
    float2 s = gather_row(row_off, deg, csr_pair, h_prev, wid, lane);
    h_out[(size_t)wid * 64 + lane] = pack_bf16x2(s.x, s.y);
}

// Fused hop (even k): s = gather; h_out = bf16(s) (skipped at k=10);
// acc = [first ? c0*x : acc] + cPrev*h_prev[own] + cCur*s.
__global__ void hop_acc_kernel(const int* __restrict__ row_off, const int* __restrict__ deg,
                               const int2* __restrict__ csr_pair,
                               const unsigned* __restrict__ h_prev, unsigned* __restrict__ h_out,
                               const float2* __restrict__ x2, float2* __restrict__ acc2,
                               const float2* __restrict__ coefPrev2,
                               const float2* __restrict__ coefCur2,
                               const float2* __restrict__ coef02,
                               int n, int first, int write_h) {
    int wid = (blockIdx.x << 2) + (threadIdx.x >> 6);
    int lane = threadIdx.x & 63;
    if (wid >= n) return;
    float2 s = gather_row(row_off, deg, csr_pair, h_prev, wid, lane);
    size_t o = (size_t)wid * 64 + lane;
    if (write_h) h_out[o] = pack_bf16x2(s.x, s.y);
    unsigned up = h_prev[o];
    float2 cP = coefPrev2[lane];
    float2 cC = coefCur2[lane];
    float2 a;
    if (first) {
        float2 xv = x2[o];
        float2 c0 = coef02[lane];
        a.x = c0.x * xv.x;
        a.y = c0.y * xv.y;
    } else {
        a = acc2[o];
    }
    a.x += cP.x * bf16lo(up) + cC.x * s.x;
    a.y += cP.y * bf16hi(up) + cC.y * s.y;
    acc2[o] = a;
}

// h1 = acc @ W1 (128x64) tiled; bf16 LDS staging (32KB -> 5 blocks/CU).
// kc loop unroll(1): full unroll spilled to scratch (round-4 regression).
__global__ __launch_bounds__(256) void gemm1_kernel(
    const float* __restrict__ acc, const float* __restrict__ W1,
    const float* __restrict__ a_s, const float* __restrict__ a_d,
    unsigned* __restrict__ h1b, float* __restrict__ als, float* __restrict__ ald, int n) {
    __shared__ unsigned short Wl16[128 * 64];  // bf16 weights, 16 KB
    __shared__ unsigned Al[4][16 * 64];        // bf16x2-packed acc rows, 16 KB
    for (int i = threadIdx.x; i < 128 * 64; i += 256)
        Wl16[i] = (unsigned short)(pack_bf16x2(W1[i], 0.f) & 0xffffu);
    int w = threadIdx.x >> 6;
    int lane = threadIdx.x & 63;
    int node0 = (blockIdx.x * 4 + w) * 16;
    const float2* acc2 = (const float2*)acc;
#pragma unroll
    for (int i = 0; i < 16; ++i) {
        int node = node0 + i;
        float2 v = (node < n) ? acc2[(size_t)node * 64 + lane] : make_float2(0.f, 0.f);
        Al[w][i * 64 + lane] = pack_bf16x2(v.x, v.y);
    }
    __syncthreads();
    float sums[16];
#pragma unroll
    for (int nd = 0; nd < 16; ++nd) sums[nd] = 0.f;
#pragma unroll 1
    for (int kc = 0; kc < 16; ++kc) {
        float wr[8];
#pragma unroll
        for (int i = 0; i < 8; ++i)
            wr[i] = __uint_as_float((unsigned)Wl16[(kc * 8 + i) * 64 + lane] << 16);
#pragma unroll
        for (int nd = 0; nd < 16; ++nd) {
            uint4 u = *(const uint4*)&Al[w][nd * 64 + kc * 4];
            float s = sums[nd];
            s = fmaf(wr[0], bf16lo(u.x), s); s = fmaf(wr[1], bf16hi(u.x), s);
            s = fmaf(wr[2], bf16lo(u.y), s); s = fmaf(wr[3], bf16hi(u.y), s);
            s = fmaf(wr[4], bf16lo(u.z), s); s = fmaf(wr[5], bf16hi(u.z), s);
            s = fmaf(wr[6], bf16lo(u.w), s); s = fmaf(wr[7], bf16hi(u.w), s);
            sums[nd] = s;
        }
    }
    float asv = a_s[lane], adv = a_d[lane];
#pragma unroll
    for (int nd = 0; nd < 16; ++nd) {
        int node = node0 + nd;
        if (node >= n) break;
        float sum = sums[nd];
        float partner = __shfl_xor(sum, 1);
        if ((lane & 1) == 0) h1b[(size_t)node * 32 + (lane >> 1)] = pack_bf16x2(sum, partner);
        float vs = sum * asv;
        float vd = sum * adv;
        vs += __shfl_xor(vs, 1); vs += __shfl_xor(vs, 2); vs += __shfl_xor(vs, 4);
        vd += __shfl_xor(vd, 1); vd += __shfl_xor(vd, 2); vd += __shfl_xor(vd, 4);
        if ((lane & 7) == 0) {
            als[(size_t)node * 8 + (lane >> 3)] = vs;
            ald[(size_t)node * 8 + (lane >> 3)] = vd;
        }
    }
}

// agg1: softmax agg without max subtraction (shift-invariant; logits O(1)).
// Half-wave edge parallelism; channel pair (2l,2l+1) bf16-packed per lane.
__global__ void agg1_kernel(const int* __restrict__ row_off, const int* __restrict__ deg,
                            const int2* __restrict__ csr_pair,
                            const unsigned* __restrict__ h1b, const float* __restrict__ als,
                            const float* __restrict__ ald, const float* __restrict__ b1,
                            float2* __restrict__ helu2, int n) {
    int wid = (blockIdx.x << 2) + (threadIdx.x >> 6);
    int lane = threadIdx.x & 63;
    if (wid >= n) return;
    int half = lane >> 5;
    int l = lane & 31;          // channel pair index
    int head = l >> 2;          // (2l)>>3
    int off = row_off[wid];
    int cnt = deg[wid];
    float aldv = ald[(size_t)wid * 8 + head];
    float dA = 0.f, dB = 0.f;
    float2 aA = {0.f, 0.f}, aB = {0.f, 0.f};
    for (int base = 0; base < cnt; base += 64) {
        int nb = min(64, cnt - base);
        int srcv = 0;
        if (lane < nb) srcv = csr_pair[off + base + lane].x;
        int j = 0;
        for (; j + 3 < nb; j += 4) {
            int sA0 = __builtin_amdgcn_readlane(srcv, j);
            int sA1 = __builtin_amdgcn_readlane(srcv, j + 1);
            int sB0 = __builtin_amdgcn_readlane(srcv, j + 2);
            int sB1 = __builtin_amdgcn_readlane(srcv, j + 3);
            int sA = half ? sA1 : sA0;
            int sB = half ? sB1 : sB0;
            float eA = als[(size_t)sA * 8 + head] + aldv;
            float eB = als[(size_t)sB * 8 + head] + aldv;
            eA = eA > 0.f ? eA : 0.2f * eA;
            eB = eB > 0.f ? eB : 0.2f * eB;
            float pA = __expf(eA);
            float pB = __expf(eB);
            unsigned uA = h1b[(size_t)sA * 32 + l];
            unsigned uB = h1b[(size_t)sB * 32 + l];
            dA += pA; dB += pB;
            aA.x = fmaf(pA, bf16lo(uA), aA.x);
            aA.y = fmaf(pA, bf16hi(uA), aA.y);
            aB.x = fmaf(pB, bf16lo(uB), aB.x);
            aB.y = fmaf(pB, bf16hi(uB), aB.y);
        }
        for (; j < nb; j += 2) {
            int s0 = __builtin_amdgcn_readlane(srcv, j);
            int s1 = (j + 1 < nb) ? __builtin_amdgcn_readlane(srcv, j + 1) : -1;
            int s = half ? s1 : s0;
            bool valid = s >= 0;
            int ss = valid ? s : 0;
            float e = als[(size_t)ss * 8 + head] + aldv;
            e = e > 0.f ? e : 0.2f * e;
            float p = valid ? __expf(e) : 0.f;
            unsigned u = h1b[(size_t)ss * 32 + l];
            dA += p;
            aA.x = fmaf(p, bf16lo(u), aA.x);
            aA.y = fmaf(p, bf16hi(u), aA.y);
        }
    }
    float d = dA + dB;
    float2 accv = make_float2(aA.x + aB.x, aA.y + aB.y);
    d += __shfl_xor(d, 32);
    accv.x += __shfl_xor(accv.x, 32);
    accv.y += __shfl_xor(accv.y, 32);
    if (half == 0) {
        float inv = 1.f / d;   // d >= exp(self-loop logit) > 0
        float ox = fmaf(accv.x, inv, b1[2 * l]);
        float oy = fmaf(accv.y, inv, b1[2 * l + 1]);
        ox = ox > 0.f ? ox : expm1f(ox);  // ELU
        oy = oy > 0.f ? oy : expm1f(oy);
        helu2[(size_t)wid * 32 + l] = make_float2(ox, oy);
    }
}

// h2 = helu @ W2 (64x40) tiled; h2 stored bf16-packed [N,20] uints.
__global__ __launch_bounds__(256) void gemm2_kernel(
    const float* __restrict__ helu, const float* __restrict__ W2,
    const float* __restrict__ a_s, const float* __restrict__ a_d,
    unsigned* __restrict__ h2b, float* __restrict__ als, float* __restrict__ ald, int n) {
    __shared__ float Wl[64 * 40];
    __shared__ float Al[4][16 * 64];
    for (int i = threadIdx.x; i < 64 * 40; i += 256) Wl[i] = W2[i];
    int w = threadIdx.x >> 6;
    int lane = threadIdx.x & 63;
    int node0 = (blockIdx.x * 4 + w) * 16;
    const float4* hv4 = (const float4*)helu;
    float4* Av4 = (float4*)Al[w];
#pragma unroll
    for (int i = 0; i < 4; ++i) {
        int f4 = i * 64 + lane;
        int g4 = node0 * 16 + f4;
        float4 v = (g4 < n * 16) ? hv4[g4] : make_float4(0.f, 0.f, 0.f, 0.f);
        Av4[f4] = v;
    }
    __syncthreads();
    bool act = lane < 40;
    int li = act ? lane : 0;
    float sums[16];
#pragma unroll
    for (int nd = 0; nd < 16; ++nd) sums[nd] = 0.f;
#pragma unroll 1
    for (int kc = 0; kc < 8; ++kc) {
        float wr[8];
#pragma unroll
        for (int i = 0; i < 8; ++i) wr[i] = Wl[(kc * 8 + i) * 40 + li];
#pragma unroll
        for (int nd = 0; nd < 16; ++nd) {
            float4 a = *(const float4*)&Al[w][nd * 64 + kc * 8];
            float4 b = *(const float4*)&Al[w][nd * 64 + kc * 8 + 4];
            float s = sums[nd];
            s = fmaf(wr[0], a.x, s); s = fmaf(wr[1], a.y, s);
            s = fmaf(wr[2], a.z, s); s = fmaf(wr[3], a.w, s);
            s = fmaf(wr[4], b.x, s); s = fmaf(wr[5], b.y, s);
            s = fmaf(wr[6], b.z, s); s = fmaf(wr[7], b.w, s);
            sums[nd] = s;
        }
    }
    float asv = act ? a_s[lane] : 0.f;
    float adv = act ? a_d[lane] : 0.f;
#pragma unroll
    for (int nd = 0; nd < 16; ++nd) {
        int node = node0 + nd;
        if (node >= n) break;
        float sum = sums[nd];
        float partner = __shfl_xor(sum, 1);
        if (act && (lane & 1) == 0) h2b[(size_t)node * 20 + (lane >> 1)] = pack_bf16x2(sum, partner);
        float vs = act ? sum * asv : 0.f;
        float vd = act ? sum * adv : 0.f;
#pragma unroll
        for (int i = 32; i >= 1; i >>= 1) { vs += __shfl_xor(vs, i); vd += __shfl_xor(vd, i); }
        if (lane == 0) { als[node] = vs; ald[node] = vd; }
    }
}

// agg2 (1 head, 40 ch): per-lane exp precompute (p broadcast via readlane —
// removes 32x-redundant exp per edge that made it VALU-bound), no-max
// softmax, half-wave edge split, fused log_softmax. Lanes >= nb hold p=0 so
// the 4-edge loop needs no tail handling.
__global__ void agg2_kernel(const int* __restrict__ row_off, const int* __restrict__ deg,
                            const int2* __restrict__ csr_pair,
                            const unsigned* __restrict__ h2b, const float* __restrict__ als,
                            const float* __restrict__ ald, const float* __restrict__ b2,
                            float* __restrict__ out, int n) {
    int wid = (blockIdx.x << 2) + (threadIdx.x >> 6);
    int lane = threadIdx.x & 63;
    if (wid >= n) return;
    int half = lane >> 5;
    int l = lane & 31;
    bool act = l < 20;          // channel pairs 0..19
    int li = act ? l : 0;
    int off = row_off[wid];
    int cnt = deg[wid];
    float aldv = ald[wid];
    float dA = 0.f, dB = 0.f;
    float2 aA = {0.f, 0.f}, aB = {0.f, 0.f};
    for (int base = 0; base < cnt; base += 64) {
        int nb = min(64, cnt - base);
        int srcv = 0;
        float pv = 0.f;
        if (lane < nb) {
            srcv = csr_pair[off + base + lane].x;
            float e = als[srcv] + aldv;
            e = e > 0.f ? e : 0.2f * e;
            pv = __expf(e);
        }
        for (int j = 0; j < nb; j += 4) {
            int sA0 = __builtin_amdgcn_readlane(srcv, j);
            int sA1 = __builtin_amdgcn_readlane(srcv, j + 1);
            int sB0 = __builtin_amdgcn_readlane(srcv, j + 2);
            int sB1 = __builtin_amdgcn_readlane(srcv, j + 3);
            float pA0 = readlane_f(pv, j);
            float pA1 = readlane_f(pv, j + 1);
            float pB0 = readlane_f(pv, j + 2);
            float pB1 = readlane_f(pv, j + 3);
            int sA = half ? sA1 : sA0;
            int sB = half ? sB1 : sB0;
            float pA = half ? pA1 : pA0;
            float pB = half ? pB1 : pB0;
            unsigned uA = h2b[(size_t)sA * 20 + li];
            unsigned uB = h2b[(size_t)sB * 20 + li];
            dA += pA; dB += pB;
            aA.x = fmaf(pA, bf16lo(uA), aA.x);
            aA.y = fmaf(pA, bf16hi(uA), aA.y);
            aB.x = fmaf(pB, bf16lo(uB), aB.x);
            aB.y = fmaf(pB, bf16hi(uB), aB.y);
        }
    }
    float d = dA + dB;
    float2 accv = make_float2(aA.x + aB.x, aA.y + aB.y);
    d += __shfl_xor(d, 32);
    accv.x += __shfl_xor(accv.x, 32);
    accv.y += __shfl_xor(accv.y, 32);
    float inv = 1.f / d;
    bool live = (half == 0) && act;
    float ox = live ? fmaf(accv.x, inv, b2[2 * l]) : -1e30f;
    float oy = live ? fmaf(accv.y, inv, b2[2 * l + 1]) : -1e30f;
    float vv = fmaxf(ox, oy);
#pragma unroll
    for (int i = 16; i >= 1; i >>= 1) vv = fmaxf(vv, __shfl_xor(vv, i));
    float ex = live ? (__expf(ox - vv) + __expf(oy - vv)) : 0.f;
#pragma unroll
    for (int i = 16; i >= 1; i >>= 1) ex += __shfl_xor(ex, i);
    if (live) {
        float lse = vv + logf(ex);
        *(float2*)&out[(size_t)wid * 40 + 2 * l] = make_float2(ox - lse, oy - lse);
    }
}

extern "C" void kernel_launch(void* const* d_in, const int* in_sizes, int n_in,
                              void* d_out, int out_size, void* d_ws, size_t ws_size,
                              hipStream_t stream) {
    const float* x    = (const float*)d_in[0];
    const int*   ei   = (const int*)d_in[1];
    const float* t    = (const float*)d_in[2];
    const float* W1   = (const float*)d_in[3];
    const float* a_s1 = (const float*)d_in[4];
    const float* a_d1 = (const float*)d_in[5];
    const float* b1   = (const float*)d_in[6];
    const float* W2   = (const float*)d_in[7];
    const float* a_s2 = (const float*)d_in[8];
    const float* a_d2 = (const float*)d_in[9];
    const float* b2   = (const float*)d_in[10];
    float* out = (float*)d_out;

    const int N = in_sizes[0] / 128;
    const int E = in_sizes[1] / 2;

    char* w = (char*)d_ws;
    auto carve = [&](size_t bytes) {
        void* p = (void*)w;
        w += (bytes + 255) & ~(size_t)255;
        return p;
    };
    int*      deg      = (int*)carve((size_t)N * 4);
    int*      row_off  = (int*)carve((size_t)N * 4);
    int*      gcount   = (int*)carve(256);
    float*    dinv     = (float*)carve((size_t)N * 4);
    int*      epos     = (int*)carve((size_t)E * 4);
    int2*     csr_pair = (int2*)carve((size_t)(E + N) * 8);
    float*    coefs    = (float*)carve(11 * 128 * 4);
    float*    als1     = (float*)carve((size_t)N * 8 * 4);
    float*    ald1     = (float*)carve((size_t)N * 8 * 4);
    float*    als2     = (float*)carve((size_t)N * 4);
    float*    ald2     = (float*)carve((size_t)N * 4);
    float*    acc      = (float*)carve((size_t)N * 128 * 4);
    unsigned* hA       = (unsigned*)carve((size_t)N * 64 * 4);  // bf16x2 per uint
    unsigned* hB       = (unsigned*)carve((size_t)N * 64 * 4);
    unsigned* h1b      = (unsigned*)carve((size_t)N * 32 * 4);  // bf16 [N,64]
    float*    helu     = (float*)carve((size_t)N * 64 * 4);
    unsigned* h2b      = (unsigned*)carve((size_t)N * 20 * 4);  // bf16 [N,40]

    dim3 blk(256);
    int gN = (N + 255) / 256;
    int gE = (E + 255) / 256;
    int gEN = (E + N + 255) / 256;
    int gW = (N + 3) / 4;        // one wave per node, 4 waves/block
    int gT = (N + 63) / 64;      // wave per 16 nodes, 4 waves/block
    int gS = (N * 32 + 255) / 256;  // streaming float4/uint2 grids

    init_node_kernel<<<gN, blk, 0, stream>>>(deg, N);
    hipMemsetAsync(gcount, 0, 4, stream);
    edge_deg_kernel<<<gE, blk, 0, stream>>>(ei + E, deg, epos, E);
    alloc_kernel<<<gN, blk, 0, stream>>>(deg, dinv, row_off, gcount, N);
    scatter_kernel<<<gEN, blk, 0, stream>>>(ei, row_off, epos, dinv, csr_pair, E, N);
    coef_kernel<<<1, 128, 0, stream>>>(t, coefs);
    init_diff_kernel<<<gS, blk, 0, stream>>>((const float4*)x, (uint2*)hA, N * 32);

    // hops 1..10; odd hops pure, even hops fuse acc += c_{k-1} h_{k-1} + c_k h_k
    // (k=2 additionally seeds acc with c0*x; k=10 skips the dead h10 write).
    unsigned* hc = hA;
    unsigned* hn = hB;
    for (int k = 1; k <= 10; ++k) {
        if (k & 1) {
            hop_kernel<<<gW, blk, 0, stream>>>(row_off, deg, csr_pair, hc, hn, N);
        } else {
            hop_acc_kernel<<<gW, blk, 0, stream>>>(
                row_off, deg, csr_pair, hc, hn, (const float2*)x, (float2*)acc,
                (const float2*)(coefs + (size_t)(k - 1) * 128),
                (const float2*)(coefs + (size_t)k * 128),
                (const float2*)coefs, N, k == 2 ? 1 : 0, k < 10 ? 1 : 0);
        }
        unsigned* tmp = hc; hc = hn; hn = tmp;
    }

    gemm1_kernel<<<gT, blk, 0, stream>>>(acc, W1, a_s1, a_d1, h1b, als1, ald1, N);
    agg1_kernel<<<gW, blk, 0, stream>>>(row_off, deg, csr_pair, h1b, als1, ald1, b1,
                                        (float2*)helu, N);
    gemm2_kernel<<<gT, blk, 0, stream>>>(helu, W2, a_s2, a_d2, h2b, als2, ald2, N);
    agg2_kernel<<<gW, blk, 0, stream>>>(row_off, deg, csr_pair, h2b, als2, ald2, b2, out, N);
}